// Round 9
// baseline (3275.476 us; speedup 1.0000x reference)
//
#include <hip/hip_runtime.h>
#include <hip/hip_bf16.h>
#include <cstdint>

#define LEAKV 0.2f
static const int Bb = 4, Nn = 4096, Mm = 16384, Kk = 20;
static const int Gg = 8;

typedef __attribute__((ext_vector_type(8))) short bf16x8;
typedef __attribute__((ext_vector_type(4))) float f32x4;

__device__ __forceinline__ float lrelu_f(float v){ return v > 0.f ? v : LEAKV*v; }

// ---------------- workspace layout (float offsets, compile-time) ----------------
// total = 18,505,728 floats = 74.02 MB  (<= 75.15 MB proven available in rounds 3-7)
constexpr size_t O_DFLAG = 0;
constexpr size_t O_XYZ   = 16;                 // 49152 fp32
constexpr size_t O_NRM   = 49168;              // 16384
constexpr size_t O_IDX   = 65552;              // 327680 (int)
constexpr size_t O_GLOB  = 393232;             // 4096 (uint)
constexpr size_t O_GV    = 397328;             // 1024
constexpr size_t O_S1 = 398352, O_B1 = 398416, O_S2 = 398480, O_B2 = 398544;
constexpr size_t O_S3 = 398608, O_B3 = 398736, O_S4 = 398864, O_B4 = 399120;
constexpr size_t O_SF = 399376, O_BF = 399888, O_SE = 400400, O_BE = 401424;
constexpr size_t O_SH1 = 402448, O_BH1 = 402704, O_SH2 = 402960, O_BH2 = 403216;
constexpr size_t O_BH3 = 403472;               // 64
constexpr size_t O_WCAT1 = 403536;             // 512 fp32 (layer1 [128][3]) ends 404048
constexpr size_t O_WBH  = 404992;              // big weights bf16 hi: 1257984 bf16 = 628992 fl
constexpr size_t O_WBL  = 1033984;             // ends 1662976
constexpr size_t O_WCATH = 1662976;            // wcat bf16 hi (65536 bf16 = 32768 fl)
constexpr size_t O_WCATL = 1695744;            // ends 1728512
constexpr size_t O_XCATH = 1728512;            // [M,512] bf16 = 4194304 fl
constexpr size_t O_XCATL = 5922816;            // ends 10117120
constexpr size_t O_REGB  = 10117120;           // 8388608 fl multipurpose; ends 18505728
// XCAT region reuse after wf GEMM (each H buf = M*256 bf16 = 2097152 fl):
constexpr size_t O_H1H = O_XCATH;              // 1728512
constexpr size_t O_H1L = O_XCATH + 2097152;    // 3825664
constexpr size_t O_H2H = O_XCATH + 4194304;    // 5922816
constexpr size_t O_H2L = O_XCATH + 6291456;    // 8019968  (ends 10117120)
// Wbig internal offsets (bf16 elements)
constexpr size_t WOF_WF = 0, WOF_WE = 262144, WOF_WH1 = 786432, WOF_WH2 = 1179648, WOF_WH3 = 1245184;
constexpr int WTOT = 1257984;

// ---------- dtype detector ----------
__global__ void detect_kernel(const void* __restrict__ xyz, int n, int* __restrict__ flag){
  __shared__ int cnt;
  if (threadIdx.x == 0) cnt = 0;
  __syncthreads();
  const __hip_bfloat16* p = (const __hip_bfloat16*)xyz;
  int local = 0;
  for (int i = threadIdx.x; i < n; i += 256){
    float v = __bfloat162float(p[i]);
    if (!(fabsf(v) < 1000.f)) local++;
  }
  atomicAdd(&cnt, local);
  __syncthreads();
  if (threadIdx.x == 0) *flag = (cnt < n/16) ? 1 : 0;   // 1 = bf16, 0 = fp32
}

__device__ __forceinline__ float rdval(const void* p, int i, int flag){
  return flag ? __bfloat162float(((const __hip_bfloat16*)p)[i]) : ((const float*)p)[i];
}

// ---------- fused small-input conversion + glob init ----------
__global__ void cvt_small_kernel(float* __restrict__ ws, const int* __restrict__ flag,
    const void* xyz, const void* s1, const void* b1, const void* s2, const void* b2,
    const void* s3, const void* b3, const void* s4, const void* b4,
    const void* sf, const void* bf, const void* se, const void* be,
    const void* sh1, const void* bh1, const void* sh2, const void* bh2, const void* bh3)
{
  int t = blockIdx.x*256 + threadIdx.x;
  int fl = *flag;
  if (t < 49152){ ws[O_XYZ + t] = rdval(xyz, t, fl); return; }
  t -= 49152;
  if (t < 4096){ ((unsigned*)(ws + O_GLOB))[t] = 0u; return; }
  t -= 4096;
  if (t < 64){ ws[O_S1+t] = rdval(s1,t,fl); return; }  t -= 64;
  if (t < 64){ ws[O_B1+t] = rdval(b1,t,fl); return; }  t -= 64;
  if (t < 64){ ws[O_S2+t] = rdval(s2,t,fl); return; }  t -= 64;
  if (t < 64){ ws[O_B2+t] = rdval(b2,t,fl); return; }  t -= 64;
  if (t < 128){ ws[O_S3+t] = rdval(s3,t,fl); return; } t -= 128;
  if (t < 128){ ws[O_B3+t] = rdval(b3,t,fl); return; } t -= 128;
  if (t < 256){ ws[O_S4+t] = rdval(s4,t,fl); return; } t -= 256;
  if (t < 256){ ws[O_B4+t] = rdval(b4,t,fl); return; } t -= 256;
  if (t < 512){ ws[O_SF+t] = rdval(sf,t,fl); return; } t -= 512;
  if (t < 512){ ws[O_BF+t] = rdval(bf,t,fl); return; } t -= 512;
  if (t < 1024){ ws[O_SE+t] = rdval(se,t,fl); return; } t -= 1024;
  if (t < 1024){ ws[O_BE+t] = rdval(be,t,fl); return; } t -= 1024;
  if (t < 256){ ws[O_SH1+t] = rdval(sh1,t,fl); return; } t -= 256;
  if (t < 256){ ws[O_BH1+t] = rdval(bh1,t,fl); return; } t -= 256;
  if (t < 256){ ws[O_SH2+t] = rdval(sh2,t,fl); return; } t -= 256;
  if (t < 256){ ws[O_BH2+t] = rdval(bh2,t,fl); return; } t -= 256;
  if (t < 50){ ws[O_BH3+t] = rdval(bh3,t,fl); return; }
}

// ---------- fused big-weight conversion -> bf16 hi/lo ----------
__global__ void cvt_w_kernel(float* __restrict__ ws, const int* __restrict__ flag,
    const void* wf, const void* we, const void* wh1, const void* wh2, const void* wh3)
{
  int t = blockIdx.x*256 + threadIdx.x;
  if (t >= WTOT) return;
  int fl = *flag;
  float v;
  if (t < (int)WOF_WE)        v = rdval(wf,  t, fl);
  else if (t < (int)WOF_WH1)  v = rdval(we,  t - WOF_WE, fl);
  else if (t < (int)WOF_WH2)  v = rdval(wh1, t - WOF_WH1, fl);
  else if (t < (int)WOF_WH3)  v = rdval(wh2, t - WOF_WH2, fl);
  else                        v = rdval(wh3, t - WOF_WH3, fl);
  __hip_bfloat16 h = __float2bfloat16(v);
  ((__hip_bfloat16*)(ws + O_WBH))[t] = h;
  ((__hip_bfloat16*)(ws + O_WBL))[t] = __float2bfloat16(v - __bfloat162float(h));
}

// ---------- edgeconv weight prep: wcat = [w_d ; w_x - w_d] -> bf16 h/l ----------
__global__ void prep_w_hl_kernel(float* __restrict__ ws, const int* __restrict__ flag,
                                 const void* __restrict__ w, int C, int O){
  int t = blockIdx.x*256 + threadIdx.x;
  if (t >= O*C) return;
  int fl = *flag;
  int o = t / C, c = t - o*C;
  float wd = rdval(w, o*2*C + c, fl);
  float wx = rdval(w, o*2*C + C + c, fl);
  float dx = wx - wd;
  __hip_bfloat16* Wh = (__hip_bfloat16*)(ws + O_WCATH);
  __hip_bfloat16* Wl = (__hip_bfloat16*)(ws + O_WCATL);
  __hip_bfloat16 h1 = __float2bfloat16(wd);
  Wh[o*C + c] = h1; Wl[o*C + c] = __float2bfloat16(wd - __bfloat162float(h1));
  __hip_bfloat16 h2 = __float2bfloat16(dx);
  Wh[(O+o)*C + c] = h2; Wl[(O+o)*C + c] = __float2bfloat16(dx - __bfloat162float(h2));
}

// layer-1 fp32 wcat [128][3]
__global__ void prep_w1_kernel(float* __restrict__ ws, const int* __restrict__ flag,
                               const void* __restrict__ w){
  int t = blockIdx.x*256 + threadIdx.x;
  if (t >= 64*3) return;
  int fl = *flag;
  int o = t / 3, c = t - o*3;
  float wd = rdval(w, o*6 + c, fl);
  float wx = rdval(w, o*6 + 3 + c, fl);
  ws[O_WCAT1 + o*3 + c] = wd;
  ws[O_WCAT1 + (64+o)*3 + c] = wx - wd;
}

// ---------- norms ----------
__global__ void norms_kernel(const float* __restrict__ x, int ld, int C, float* __restrict__ out){
  int t = blockIdx.x*256 + threadIdx.x;
  if (t >= Mm) return;
  const float* r = x + (size_t)t*ld;
  float s = 0.f;
  for (int c = 0; c < C; ++c){ float v = r[c]; s += v*v; }
  out[t] = s;
}
__global__ void norms_hl_kernel(const __hip_bfloat16* __restrict__ Xh, const __hip_bfloat16* __restrict__ Xl,
                                int ld, int C, float* __restrict__ out){
  int t = blockIdx.x*256 + threadIdx.x;
  if (t >= Mm) return;
  size_t base = (size_t)t*ld;
  float s = 0.f;
  for (int c = 0; c < C; ++c){
    float v = __bfloat162float(Xh[base+c]) + __bfloat162float(Xl[base+c]);
    s += v*v;
  }
  out[t] = s;
}

// ---------- MFMA KNN: wave owns 16 queries; 3-pass bf16 hi/lo distances ----------
template<int C>
__global__ __launch_bounds__(256, 4) void knn_mfma_kernel(
    const __hip_bfloat16* __restrict__ Xh, const __hip_bfloat16* __restrict__ Xl, int lda,
    const float* __restrict__ n2,
    float* __restrict__ outd, int* __restrict__ outi)
{
  constexpr int KS = C/32;
  __shared__ float Dt[4][16*17];
  const int tid = threadIdx.x;
  const int lane = tid & 63;
  const int w = tid >> 6;
  const int b = blockIdx.z, bN = b*Nn;
  const int q0 = blockIdx.x*64 + w*16;
  const int g = blockIdx.y;
  const int kq = (lane >> 4) * 8;

  bf16x8 Ah[KS], Al[KS];
  {
    const size_t qrow = (size_t)(bN + q0 + (lane & 15))*lda;
    #pragma unroll
    for (int s = 0; s < KS; ++s){
      Ah[s] = *reinterpret_cast<const bf16x8*>(Xh + qrow + s*32 + kq);
      Al[s] = *reinterpret_cast<const bf16x8*>(Xl + qrow + s*32 + kq);
    }
  }

  float bd[20]; int bi[20];
  #pragma unroll
  for (int l = 0; l < 20; ++l){ bd[l] = 1e30f; bi[l] = 0x7fffffff; }
  float worst = 1e30f; int wp = 0;

  const int NT = (Nn/Gg)/16;
  float* dtw = Dt[w];
  for (int jt = 0; jt < NT; ++jt){
    const int j0 = g*(Nn/Gg) + jt*16;
    const size_t crow = (size_t)(bN + j0 + (lane & 15))*lda;
    f32x4 acc = {0.f, 0.f, 0.f, 0.f};
    #pragma unroll
    for (int s = 0; s < KS; ++s){
      bf16x8 Bh = *reinterpret_cast<const bf16x8*>(Xh + crow + s*32 + kq);
      bf16x8 Bl = *reinterpret_cast<const bf16x8*>(Xl + crow + s*32 + kq);
      acc = __builtin_amdgcn_mfma_f32_16x16x32_bf16(Ah[s], Bh, acc, 0, 0, 0);
      acc = __builtin_amdgcn_mfma_f32_16x16x32_bf16(Ah[s], Bl, acc, 0, 0, 0);
      acc = __builtin_amdgcn_mfma_f32_16x16x32_bf16(Al[s], Bh, acc, 0, 0, 0);
    }
    float nj = n2[bN + j0 + (lane & 15)];
    const int rbase = (lane >> 4)*4;
    #pragma unroll
    for (int r = 0; r < 4; ++r)
      dtw[(rbase + r)*17 + (lane & 15)] = nj - 2.f*acc[r];
    const float* rowp = dtw + (lane >> 2)*17 + (lane & 3)*4;
    #pragma unroll
    for (int t = 0; t < 4; ++t){
      float d = rowp[t];
      if (d < worst){
        int j = j0 + (lane & 3)*4 + t;
        #pragma unroll
        for (int l = 0; l < 20; ++l) if (l == wp){ bd[l] = d; bi[l] = j; }
        worst = bd[0]; wp = 0;
        #pragma unroll
        for (int l = 1; l < 20; ++l) if (bd[l] > worst){ worst = bd[l]; wp = l; }
      }
    }
  }

  // merge each query's 4 partial lists via shfl; leader = lane%4==0
  float wd_ = bd[0]; int wi_ = bi[0]; int wp_ = 0;
  #pragma unroll
  for (int l = 1; l < 20; ++l)
    if (bd[l] > wd_ || (bd[l] == wd_ && bi[l] > wi_)){ wd_ = bd[l]; wi_ = bi[l]; wp_ = l; }
  const bool leader = (lane & 3) == 0;
  for (int p = 1; p < 4; ++p){
    #pragma unroll
    for (int l = 0; l < 20; ++l){
      float od = __shfl(bd[l], (lane & 60) + p, 64);
      int   oi = __shfl(bi[l], (lane & 60) + p, 64);
      bool better = leader && ((od < wd_) || (od == wd_ && oi < wi_));
      if (better){
        #pragma unroll
        for (int l2 = 0; l2 < 20; ++l2) if (l2 == wp_){ bd[l2] = od; bi[l2] = oi; }
        wd_ = bd[0]; wi_ = bi[0]; wp_ = 0;
        #pragma unroll
        for (int l2 = 1; l2 < 20; ++l2)
          if (bd[l2] > wd_ || (bd[l2] == wd_ && bi[l2] > wi_)){ wd_ = bd[l2]; wi_ = bi[l2]; wp_ = l2; }
      }
    }
  }
  if (leader){
    const int q = q0 + (lane >> 2);
    size_t base = ((size_t)(bN + q)*Gg + g)*20;
    #pragma unroll
    for (int l = 0; l < 20; ++l){ outd[base + l] = bd[l]; outi[base + l] = bi[l]; }
  }
}

// ---------- KNN for C=3 ----------
__global__ __launch_bounds__(256, 4) void knn3_kernel(
    const float* __restrict__ x, const float* __restrict__ n2,
    float* __restrict__ outd, int* __restrict__ outi)
{
  __shared__ __align__(16) float cs[512*4];
  const int tid = threadIdx.x;
  const int b = blockIdx.z, bN = b*Nn;
  const int g = blockIdx.y;                 // 0..7
  const int q = blockIdx.x*256 + tid;
  float qx = x[(size_t)(bN+q)*3 + 0];
  float qy = x[(size_t)(bN+q)*3 + 1];
  float qz = x[(size_t)(bN+q)*3 + 2];
  for (int e = tid; e < 512; e += 256){
    int j = g*512 + e;
    cs[e*4+0] = x[(size_t)(bN+j)*3 + 0];
    cs[e*4+1] = x[(size_t)(bN+j)*3 + 1];
    cs[e*4+2] = x[(size_t)(bN+j)*3 + 2];
    cs[e*4+3] = n2[bN+j];
  }
  __syncthreads();
  float bd[20]; int bi[20];
  #pragma unroll
  for (int l = 0; l < 20; ++l){ bd[l] = 1e30f; bi[l] = 0x7fffffff; }
  float worst = 1e30f; int wp = 0;
  for (int t = 0; t < 512; ++t){
    float4 c = *reinterpret_cast<const float4*>(&cs[t*4]);
    float d = c.w - 2.f*(qx*c.x + qy*c.y + qz*c.z);
    if (d < worst){
      int j = g*512 + t;
      #pragma unroll
      for (int l = 0; l < 20; ++l) if (l == wp){ bd[l] = d; bi[l] = j; }
      worst = bd[0]; wp = 0;
      #pragma unroll
      for (int l = 1; l < 20; ++l) if (bd[l] > worst){ worst = bd[l]; wp = l; }
    }
  }
  size_t base = ((size_t)(bN + q)*Gg + g)*20;
  #pragma unroll
  for (int l = 0; l < 20; ++l){ outd[base + l] = bd[l]; outi[base + l] = bi[l]; }
}

// ---------- final merge: G lists of 20 -> top-20 ----------
__global__ __launch_bounds__(256, 4) void knn_final_merge_kernel(
    const float* __restrict__ ind, const int* __restrict__ ini,
    int* __restrict__ idx)
{
  int t = blockIdx.x*256 + threadIdx.x;
  if (t >= Mm) return;
  size_t base = (size_t)t*Gg*20;
  float fd[20]; int fi[20];
  #pragma unroll
  for (int l = 0; l < 20; ++l){ fd[l] = 1e30f; fi[l] = 0x7fffffff; }
  float wd_ = 1e30f; int wi_ = 0x7fffffff; int wp_ = 0;
  for (int e = 0; e < Gg*20; ++e){
    float d = ind[base + e];
    int   id = ini[base + e];
    bool better = (d < wd_) || (d == wd_ && id < wi_);
    if (better){
      #pragma unroll
      for (int l = 0; l < 20; ++l) if (l == wp_){ fd[l] = d; fi[l] = id; }
      wd_ = fd[0]; wi_ = fi[0]; wp_ = 0;
      #pragma unroll
      for (int l = 1; l < 20; ++l)
        if (fd[l] > wd_ || (fd[l] == wd_ && fi[l] > wi_)){ wd_ = fd[l]; wi_ = fi[l]; wp_ = l; }
    }
  }
  #pragma unroll
  for (int l = 0; l < 20; ++l) idx[(size_t)t*Kk + l] = fi[l];
}

// ---------- gather-max epilogue: fp32 tb -> bf16 h/l activations ----------
__global__ void gathermax_kernel(const float* __restrict__ tb, const int* __restrict__ idx,
                                 const float* __restrict__ sv, const float* __restrict__ bv,
                                 int O, __hip_bfloat16* __restrict__ outh,
                                 __hip_bfloat16* __restrict__ outl, int ldo)
{
  int t = blockIdx.x*256 + threadIdx.x;
  int o = t % O;
  int m = t / O;           // b*N + i
  int b = m / Nn;
  const int twoO = 2*O;
  const int* ip = idx + (size_t)m*Kk;
  float mx = -1e30f;
  for (int j = 0; j < Kk; ++j){
    int jj = ip[j] & (Nn-1);
    mx = fmaxf(mx, tb[(size_t)(b*Nn + jj)*twoO + o]);
  }
  float basev = tb[(size_t)m*twoO + O + o];
  float y = lrelu_f((mx + basev) * sv[o] + bv[o]);
  __hip_bfloat16 h = __float2bfloat16(y);
  outh[(size_t)m*ldo + o] = h;
  outl[(size_t)m*ldo + o] = __float2bfloat16(y - __bfloat162float(h));
}

// ---------- ordered-uint float max keys ----------
__device__ __forceinline__ unsigned fkey(float f){
  unsigned u = __float_as_uint(f);
  return (u & 0x80000000u) ? ~u : (u | 0x80000000u);
}
__device__ __forceinline__ float funkey(unsigned k){
  if (k == 0u) return -1e30f;
  unsigned u = (k & 0x80000000u) ? (k ^ 0x80000000u) : ~k;
  return __uint_as_float(u);
}

// ---------- MFMA GEMM: C[M,O] = (Ah+Al)[M,K] @ (Wh+Wl)[O,K]^T, hi/lo 3-pass ----------
__global__ __launch_bounds__(256, 2) void mfma_gemm_kernel(
    const __hip_bfloat16* __restrict__ Ah, const __hip_bfloat16* __restrict__ Al, int lda,
    const __hip_bfloat16* __restrict__ Wh, const __hip_bfloat16* __restrict__ Wl, int ldw,
    float* __restrict__ Cf, __hip_bfloat16* __restrict__ Ch, __hip_bfloat16* __restrict__ Cl, int ldc,
    int K, int O,
    const float* __restrict__ scale, const float* __restrict__ bias,
    const float* __restrict__ addvec, int lrelu_flag,
    unsigned* __restrict__ pool)
{
  __shared__ float red[4][64];
  const int tid = threadIdx.x;
  const int lane = tid & 63, w = tid >> 6;
  const int o0 = blockIdx.x*64, m0 = blockIdx.y*64;
  const int row = m0 + w*16 + (lane & 15);
  const int kq = (lane >> 4)*8;
  f32x4 acc[4] = {{0,0,0,0},{0,0,0,0},{0,0,0,0},{0,0,0,0}};
  const __hip_bfloat16* pa_h = Ah + (size_t)row*lda + kq;
  const __hip_bfloat16* pa_l = Al + (size_t)row*lda + kq;
  int colc[4];
  const __hip_bfloat16 *pb_h[4], *pb_l[4];
  #pragma unroll
  for (int ct = 0; ct < 4; ++ct){
    int o = o0 + ct*16 + (lane & 15);
    colc[ct] = o;
    int oc = (o < O) ? o : (O-1);
    pb_h[ct] = Wh + (size_t)oc*ldw + kq;
    pb_l[ct] = Wl + (size_t)oc*ldw + kq;
  }
  for (int k0 = 0; k0 < K; k0 += 32){
    bf16x8 a_h = *reinterpret_cast<const bf16x8*>(pa_h + k0);
    bf16x8 a_l = *reinterpret_cast<const bf16x8*>(pa_l + k0);
    #pragma unroll
    for (int ct = 0; ct < 4; ++ct){
      bf16x8 b_h = *reinterpret_cast<const bf16x8*>(pb_h[ct] + k0);
      bf16x8 b_l = *reinterpret_cast<const bf16x8*>(pb_l[ct] + k0);
      acc[ct] = __builtin_amdgcn_mfma_f32_16x16x32_bf16(a_h, b_h, acc[ct], 0, 0, 0);
      acc[ct] = __builtin_amdgcn_mfma_f32_16x16x32_bf16(a_h, b_l, acc[ct], 0, 0, 0);
      acc[ct] = __builtin_amdgcn_mfma_f32_16x16x32_bf16(a_l, b_h, acc[ct], 0, 0, 0);
    }
  }
  const int b = m0 / Nn;
  if (pool){
    #pragma unroll
    for (int ct = 0; ct < 4; ++ct){
      int o = colc[ct];
      float sc_ = scale[o], bi_ = bias[o];
      float m = -1e30f;
      #pragma unroll
      for (int r = 0; r < 4; ++r) m = fmaxf(m, lrelu_f(acc[ct][r]*sc_ + bi_));
      m = fmaxf(m, __shfl_xor(m, 16, 64));
      m = fmaxf(m, __shfl_xor(m, 32, 64));
      if ((lane >> 4) == 0) red[w][ct*16 + (lane & 15)] = m;
    }
    __syncthreads();
    if (tid < 64){
      float m = fmaxf(fmaxf(red[0][tid], red[1][tid]), fmaxf(red[2][tid], red[3][tid]));
      atomicMax(&pool[b*O + o0 + tid], fkey(m));
    }
    return;
  }
  #pragma unroll
  for (int ct = 0; ct < 4; ++ct){
    int o = colc[ct];
    if (o >= O) continue;
    float sc_ = scale ? scale[o] : 1.f;
    float bi_ = bias ? bias[o] : 0.f;
    float av  = addvec ? addvec[b*O + o] : 0.f;
    #pragma unroll
    for (int r = 0; r < 4; ++r){
      int m = m0 + w*16 + (lane >> 4)*4 + r;
      float y = acc[ct][r] + av;
      if (scale) y = y*sc_ + bi_;
      else       y = y + bi_;
      if (lrelu_flag) y = lrelu_f(y);
      if (Ch){
        __hip_bfloat16 h = __float2bfloat16(y);
        Ch[(size_t)m*ldc + o] = h;
        Cl[(size_t)m*ldc + o] = __float2bfloat16(y - __bfloat162float(h));
      } else {
        Cf[(size_t)m*ldc + o] = y;
      }
    }
  }
}

// ---------- fp32 GEMM (layer-1 tb only, K=3) ----------
__global__ __launch_bounds__(256) void gemm_kernel(
    const float* __restrict__ A, int lda,
    const float* __restrict__ W, int ldw,
    float* __restrict__ Cf, int ldc, int K, int O)
{
  const int tid = threadIdx.x;
  const int tx = tid & 15, ty = tid >> 4;
  const int m0 = blockIdx.y * 64;
  const int o0 = blockIdx.x * 64;
  __shared__ __align__(16) float As[16*68];
  __shared__ __align__(16) float Ws[16*68];
  float acc[4][4] = {};
  for (int k0 = 0; k0 < K; k0 += 16){
    __syncthreads();
    #pragma unroll
    for (int r = 0; r < 4; ++r){
      int e = tid + r*256;
      int k = e & 15, mi = e >> 4;
      int kk = k0 + k;
      float v = 0.f, wv = 0.f;
      if (kk < K) v = A[(size_t)(m0+mi)*lda + kk];
      int oo = o0 + mi;
      if (kk < K && oo < O) wv = W[(size_t)oo*ldw + kk];
      As[k*68 + mi] = v;
      Ws[k*68 + mi] = wv;
    }
    __syncthreads();
    #pragma unroll
    for (int kk = 0; kk < 16; ++kk){
      float4 av = *reinterpret_cast<const float4*>(&As[kk*68 + ty*4]);
      float4 wv = *reinterpret_cast<const float4*>(&Ws[kk*68 + tx*4]);
      float a4[4] = {av.x, av.y, av.z, av.w};
      float w4[4] = {wv.x, wv.y, wv.z, wv.w};
      #pragma unroll
      for (int i = 0; i < 4; ++i)
        #pragma unroll
        for (int j = 0; j < 4; ++j)
          acc[i][j] += a4[i]*w4[j];
    }
  }
  #pragma unroll
  for (int i = 0; i < 4; ++i){
    int m = m0 + ty*4 + i;
    #pragma unroll
    for (int j = 0; j < 4; ++j){
      int o = o0 + tx*4 + j;
      if (o >= O) continue;
      Cf[(size_t)m*ldc + o] = acc[i][j];
    }
  }
}

// gvec[b,o2] = sum_c wh1[o2, 512+c] * glob[b,c]  (one wave per (b,o2))
__global__ void gvec_kernel(const __hip_bfloat16* __restrict__ Wh, const __hip_bfloat16* __restrict__ Wl,
                            const unsigned* __restrict__ glob, float* __restrict__ gv){
  int lane = threadIdx.x & 63, w = threadIdx.x >> 6;
  int o2 = blockIdx.x*4 + w;
  int b = blockIdx.y;
  size_t base = (size_t)o2*1536 + 512;
  float s = 0.f;
  for (int c = lane; c < 1024; c += 64){
    float wv = __bfloat162float(Wh[base+c]) + __bfloat162float(Wl[base+c]);
    s += wv * funkey(glob[b*1024 + c]);
  }
  #pragma unroll
  for (int off = 32; off >= 1; off >>= 1) s += __shfl_xor(s, off, 64);
  if (lane == 0) gv[b*256 + o2] = s;
}

// ---------- flag-gated output store ----------
__global__ void store_out_kernel(const float* __restrict__ src, const int* __restrict__ flag,
                                 void* __restrict__ dst, int n){
  int t = blockIdx.x*256 + threadIdx.x;
  if (t >= n) return;
  float v = src[t];
  if (*flag) ((__hip_bfloat16*)dst)[t] = __float2bfloat16(v);
  else       ((float*)dst)[t] = v;
}

extern "C" void kernel_launch(void* const* d_in, const int* in_sizes, int n_in,
                              void* d_out, int out_size, void* d_ws, size_t ws_size,
                              hipStream_t stream) {
  (void)in_sizes; (void)n_in; (void)out_size; (void)ws_size;
  float* ws = (float*)d_ws;
  int* dflag = (int*)(ws + O_DFLAG);
  float* xyzf = ws + O_XYZ;
  float* nrm  = ws + O_NRM;
  int*   idx  = (int*)(ws + O_IDX);
  unsigned* glob = (unsigned*)(ws + O_GLOB);
  float* gv = ws + O_GV;
  __hip_bfloat16* WBH = (__hip_bfloat16*)(ws + O_WBH);
  __hip_bfloat16* WBL = (__hip_bfloat16*)(ws + O_WBL);
  __hip_bfloat16* WCH = (__hip_bfloat16*)(ws + O_WCATH);
  __hip_bfloat16* WCL = (__hip_bfloat16*)(ws + O_WCATL);
  __hip_bfloat16* XCH = (__hip_bfloat16*)(ws + O_XCATH);
  __hip_bfloat16* XCL = (__hip_bfloat16*)(ws + O_XCATL);
  // REGB multipurpose (strictly sequential uses):
  float* regB = ws + O_REGB;
  float* dpart = regB;                                   // [M][8][20] fl
  int*   ipart = (int*)(regB + (size_t)Mm*Gg*20);        // [M][8][20] int
  float* tb    = regB;                                   // [M, <=512] fp32
  __hip_bfloat16* XLH = (__hip_bfloat16*)regB;           // [M,512] bf16 (after edgeconvs)
  __hip_bfloat16* XLL = (__hip_bfloat16*)(regB + 4194304);
  float* logitsF = regB;                                 // [M,50] (XLOC dead after h1 GEMM)
  // XCAT region reuse after wf GEMM:
  __hip_bfloat16* H1H = (__hip_bfloat16*)(ws + O_H1H);
  __hip_bfloat16* H1L = (__hip_bfloat16*)(ws + O_H1L);
  __hip_bfloat16* H2H = (__hip_bfloat16*)(ws + O_H2H);
  __hip_bfloat16* H2L = (__hip_bfloat16*)(ws + O_H2L);

  // ---- detect + fused conversions ----
  detect_kernel<<<1, 256, 0, stream>>>(d_in[0], Mm*3, dflag);
  cvt_small_kernel<<<(49152+4096+5200+255)/256, 256, 0, stream>>>(ws, dflag,
      d_in[0], d_in[3], d_in[4], d_in[6], d_in[7], d_in[9], d_in[10], d_in[12], d_in[13],
      d_in[15], d_in[16], d_in[18], d_in[19], d_in[21], d_in[22], d_in[24], d_in[25], d_in[27]);
  cvt_w_kernel<<<(WTOT+255)/256, 256, 0, stream>>>(ws, dflag,
      d_in[14], d_in[17], d_in[20], d_in[23], d_in[26]);

  auto mgemm = [&](const __hip_bfloat16* Ah, const __hip_bfloat16* Al, int lda,
                   const __hip_bfloat16* Wh, const __hip_bfloat16* Wl, int ldw,
                   float* Cf, __hip_bfloat16* Ch, __hip_bfloat16* Cl, int ldc,
                   int K, int O, const float* sc, const float* bi, const float* av,
                   int lr, unsigned* pool){
    dim3 g((O+63)/64, Mm/64);
    mfma_gemm_kernel<<<g, 256, 0, stream>>>(Ah, Al, lda, Wh, Wl, ldw, Cf, Ch, Cl, ldc,
                                            K, O, sc, bi, av, lr, pool);
  };

  // ---- edgeconv layer 1 (C=3) ----
  norms_kernel<<<Mm/256, 256, 0, stream>>>(xyzf, 3, 3, nrm);
  knn3_kernel<<<dim3(Nn/256, Gg, Bb), 256, 0, stream>>>(xyzf, nrm, dpart, ipart);
  knn_final_merge_kernel<<<Mm/256, 256, 0, stream>>>(dpart, ipart, idx);
  prep_w1_kernel<<<1, 256, 0, stream>>>(ws, dflag, d_in[2]);
  gemm_kernel<<<dim3(2, Mm/64), 256, 0, stream>>>(xyzf, 3, ws + O_WCAT1, 3, tb, 128, 3, 128);
  gathermax_kernel<<<((size_t)Mm*64)/256, 256, 0, stream>>>(
      tb, idx, ws+O_S1, ws+O_B1, 64, XCH + 0, XCL + 0, 512);

  // ---- edgeconv layers 2-4 (MFMA path) ----
  struct LayerDef { int coff; int C; int O; size_t so, bo; int win; };
  LayerDef L[3] = {
    {0,   64, 64,  O_S2, O_B2, 5},
    {64,  64, 128, O_S3, O_B3, 8},
    {128, 128, 256, O_S4, O_B4, 11},
  };
  for (int li = 0; li < 3; ++li){
    int C = L[li].C, O = L[li].O, coff = L[li].coff;
    norms_hl_kernel<<<Mm/256, 256, 0, stream>>>(XCH + coff, XCL + coff, 512, C, nrm);
    if (C == 64)
      knn_mfma_kernel<64><<<dim3(Nn/64, Gg, Bb), 256, 0, stream>>>(XCH + coff, XCL + coff, 512, nrm, dpart, ipart);
    else
      knn_mfma_kernel<128><<<dim3(Nn/64, Gg, Bb), 256, 0, stream>>>(XCH + coff, XCL + coff, 512, nrm, dpart, ipart);
    knn_final_merge_kernel<<<Mm/256, 256, 0, stream>>>(dpart, ipart, idx);
    prep_w_hl_kernel<<<(O*C+255)/256, 256, 0, stream>>>(ws, dflag, d_in[L[li].win], C, O);
    mgemm(XCH + coff, XCL + coff, 512, WCH, WCL, C, tb, nullptr, nullptr, 2*O, C, 2*O,
          nullptr, nullptr, nullptr, 0, nullptr);
    gathermax_kernel<<<((size_t)Mm*O)/256, 256, 0, stream>>>(
        tb, idx, ws + L[li].so, ws + L[li].bo, O, XCH + coff + C, XCL + coff + C, 512);
  }

  // ---- chain ----
  // x_local = lrelu((x_cat @ wf^T)*sf + bf)   (tb dead -> REGB holds XLOC h/l)
  mgemm(XCH, XCL, 512, WBH + WOF_WF, WBL + WOF_WF, 512, nullptr, XLH, XLL, 512,
        512, 512, ws+O_SF, ws+O_BF, nullptr, 1, nullptr);
  // x_emb GEMM fused with global max pool -> glob (XCAT dead from here)
  mgemm(XLH, XLL, 512, WBH + WOF_WE, WBL + WOF_WE, 512, nullptr, nullptr, nullptr, 0,
        512, 1024, ws+O_SE, ws+O_BE, nullptr, 1, glob);
  gvec_kernel<<<dim3(64, Bb), 256, 0, stream>>>(WBH + WOF_WH1, WBL + WOF_WH1, glob, gv);
  // h1 = lrelu((x_local @ wh1[:, :512]^T + gvec)*sh1 + bh1)  -> XCAT region
  mgemm(XLH, XLL, 512, WBH + WOF_WH1, WBL + WOF_WH1, 1536, nullptr, H1H, H1L, 256,
        512, 256, ws+O_SH1, ws+O_BH1, gv, 1, nullptr);
  // h2 -> XCAT region (XLOC dead after h1 GEMM)
  mgemm(H1H, H1L, 256, WBH + WOF_WH2, WBL + WOF_WH2, 256, nullptr, H2H, H2L, 256,
        256, 256, ws+O_SH2, ws+O_BH2, nullptr, 1, nullptr);
  // logits -> REGB (free)
  mgemm(H2H, H2L, 256, WBH + WOF_WH3, WBL + WOF_WH3, 256, logitsF, nullptr, nullptr, 50,
        256, 50, nullptr, ws+O_BH3, nullptr, 0, nullptr);
  store_out_kernel<<<((size_t)Mm*50 + 255)/256, 256, 0, stream>>>(logitsF, dflag, d_out, Mm*50);
}

// Round 10
// 2953.502 us; speedup vs baseline: 1.1090x; 1.1090x over previous
//
#include <hip/hip_runtime.h>
#include <hip/hip_bf16.h>
#include <cstdint>

#define LEAKV 0.2f
static const int Bb = 4, Nn = 4096, Mm = 16384, Kk = 20;
static const int Gg = 8;

typedef __attribute__((ext_vector_type(8))) short bf16x8;
typedef __attribute__((ext_vector_type(4))) float f32x4;

__device__ __forceinline__ float lrelu_f(float v){ return v > 0.f ? v : LEAKV*v; }

// ---------------- workspace layout (float offsets, compile-time) ----------------
// total = 18,505,728 floats = 74.02 MB
constexpr size_t O_DFLAG = 0;
constexpr size_t O_XYZ   = 16;
constexpr size_t O_NRM   = 49168;
constexpr size_t O_IDX   = 65552;
constexpr size_t O_GLOB  = 393232;
constexpr size_t O_GV    = 397328;
constexpr size_t O_S1 = 398352, O_B1 = 398416, O_S2 = 398480, O_B2 = 398544;
constexpr size_t O_S3 = 398608, O_B3 = 398736, O_S4 = 398864, O_B4 = 399120;
constexpr size_t O_SF = 399376, O_BF = 399888, O_SE = 400400, O_BE = 401424;
constexpr size_t O_SH1 = 402448, O_BH1 = 402704, O_SH2 = 402960, O_BH2 = 403216;
constexpr size_t O_BH3 = 403472;
constexpr size_t O_WCAT1 = 403536;
constexpr size_t O_WBH  = 404992;
constexpr size_t O_WBL  = 1033984;
constexpr size_t O_WCATH = 1662976;
constexpr size_t O_WCATL = 1695744;
constexpr size_t O_XCATH = 1728512;
constexpr size_t O_XCATL = 5922816;
constexpr size_t O_REGB  = 10117120;
constexpr size_t O_H1H = O_XCATH;
constexpr size_t O_H1L = O_XCATH + 2097152;
constexpr size_t O_H2H = O_XCATH + 4194304;
constexpr size_t O_H2L = O_XCATH + 6291456;
constexpr size_t WOF_WF = 0, WOF_WE = 262144, WOF_WH1 = 786432, WOF_WH2 = 1179648, WOF_WH3 = 1245184;
constexpr int WTOT = 1257984;

// ---------- dtype detector ----------
__global__ void detect_kernel(const void* __restrict__ xyz, int n, int* __restrict__ flag){
  __shared__ int cnt;
  if (threadIdx.x == 0) cnt = 0;
  __syncthreads();
  const __hip_bfloat16* p = (const __hip_bfloat16*)xyz;
  int local = 0;
  for (int i = threadIdx.x; i < n; i += 256){
    float v = __bfloat162float(p[i]);
    if (!(fabsf(v) < 1000.f)) local++;
  }
  atomicAdd(&cnt, local);
  __syncthreads();
  if (threadIdx.x == 0) *flag = (cnt < n/16) ? 1 : 0;   // 1 = bf16, 0 = fp32
}

__device__ __forceinline__ float rdval(const void* p, int i, int flag){
  return flag ? __bfloat162float(((const __hip_bfloat16*)p)[i]) : ((const float*)p)[i];
}

// ---------- fused small-input conversion + glob init ----------
__global__ void cvt_small_kernel(float* __restrict__ ws, const int* __restrict__ flag,
    const void* xyz, const void* s1, const void* b1, const void* s2, const void* b2,
    const void* s3, const void* b3, const void* s4, const void* b4,
    const void* sf, const void* bf, const void* se, const void* be,
    const void* sh1, const void* bh1, const void* sh2, const void* bh2, const void* bh3)
{
  int t = blockIdx.x*256 + threadIdx.x;
  int fl = *flag;
  if (t < 49152){ ws[O_XYZ + t] = rdval(xyz, t, fl); return; }
  t -= 49152;
  if (t < 4096){ ((unsigned*)(ws + O_GLOB))[t] = 0u; return; }
  t -= 4096;
  if (t < 64){ ws[O_S1+t] = rdval(s1,t,fl); return; }  t -= 64;
  if (t < 64){ ws[O_B1+t] = rdval(b1,t,fl); return; }  t -= 64;
  if (t < 64){ ws[O_S2+t] = rdval(s2,t,fl); return; }  t -= 64;
  if (t < 64){ ws[O_B2+t] = rdval(b2,t,fl); return; }  t -= 64;
  if (t < 128){ ws[O_S3+t] = rdval(s3,t,fl); return; } t -= 128;
  if (t < 128){ ws[O_B3+t] = rdval(b3,t,fl); return; } t -= 128;
  if (t < 256){ ws[O_S4+t] = rdval(s4,t,fl); return; } t -= 256;
  if (t < 256){ ws[O_B4+t] = rdval(b4,t,fl); return; } t -= 256;
  if (t < 512){ ws[O_SF+t] = rdval(sf,t,fl); return; } t -= 512;
  if (t < 512){ ws[O_BF+t] = rdval(bf,t,fl); return; } t -= 512;
  if (t < 1024){ ws[O_SE+t] = rdval(se,t,fl); return; } t -= 1024;
  if (t < 1024){ ws[O_BE+t] = rdval(be,t,fl); return; } t -= 1024;
  if (t < 256){ ws[O_SH1+t] = rdval(sh1,t,fl); return; } t -= 256;
  if (t < 256){ ws[O_BH1+t] = rdval(bh1,t,fl); return; } t -= 256;
  if (t < 256){ ws[O_SH2+t] = rdval(sh2,t,fl); return; } t -= 256;
  if (t < 256){ ws[O_BH2+t] = rdval(bh2,t,fl); return; } t -= 256;
  if (t < 50){ ws[O_BH3+t] = rdval(bh3,t,fl); return; }
}

// ---------- fused big-weight conversion -> bf16 hi/lo ----------
__global__ void cvt_w_kernel(float* __restrict__ ws, const int* __restrict__ flag,
    const void* wf, const void* we, const void* wh1, const void* wh2, const void* wh3)
{
  int t = blockIdx.x*256 + threadIdx.x;
  if (t >= WTOT) return;
  int fl = *flag;
  float v;
  if (t < (int)WOF_WE)        v = rdval(wf,  t, fl);
  else if (t < (int)WOF_WH1)  v = rdval(we,  t - WOF_WE, fl);
  else if (t < (int)WOF_WH2)  v = rdval(wh1, t - WOF_WH1, fl);
  else if (t < (int)WOF_WH3)  v = rdval(wh2, t - WOF_WH2, fl);
  else                        v = rdval(wh3, t - WOF_WH3, fl);
  __hip_bfloat16 h = __float2bfloat16(v);
  ((__hip_bfloat16*)(ws + O_WBH))[t] = h;
  ((__hip_bfloat16*)(ws + O_WBL))[t] = __float2bfloat16(v - __bfloat162float(h));
}

// ---------- edgeconv weight prep: wcat = [w_d ; w_x - w_d] -> bf16 h/l ----------
__global__ void prep_w_hl_kernel(float* __restrict__ ws, const int* __restrict__ flag,
                                 const void* __restrict__ w, int C, int O){
  int t = blockIdx.x*256 + threadIdx.x;
  if (t >= O*C) return;
  int fl = *flag;
  int o = t / C, c = t - o*C;
  float wd = rdval(w, o*2*C + c, fl);
  float wx = rdval(w, o*2*C + C + c, fl);
  float dx = wx - wd;
  __hip_bfloat16* Wh = (__hip_bfloat16*)(ws + O_WCATH);
  __hip_bfloat16* Wl = (__hip_bfloat16*)(ws + O_WCATL);
  __hip_bfloat16 h1 = __float2bfloat16(wd);
  Wh[o*C + c] = h1; Wl[o*C + c] = __float2bfloat16(wd - __bfloat162float(h1));
  __hip_bfloat16 h2 = __float2bfloat16(dx);
  Wh[(O+o)*C + c] = h2; Wl[(O+o)*C + c] = __float2bfloat16(dx - __bfloat162float(h2));
}

// layer-1 fp32 wcat [128][3]
__global__ void prep_w1_kernel(float* __restrict__ ws, const int* __restrict__ flag,
                               const void* __restrict__ w){
  int t = blockIdx.x*256 + threadIdx.x;
  if (t >= 64*3) return;
  int fl = *flag;
  int o = t / 3, c = t - o*3;
  float wd = rdval(w, o*6 + c, fl);
  float wx = rdval(w, o*6 + 3 + c, fl);
  ws[O_WCAT1 + o*3 + c] = wd;
  ws[O_WCAT1 + (64+o)*3 + c] = wx - wd;
}

// ---------- norms ----------
__global__ void norms_kernel(const float* __restrict__ x, int ld, int C, float* __restrict__ out){
  int t = blockIdx.x*256 + threadIdx.x;
  if (t >= Mm) return;
  const float* r = x + (size_t)t*ld;
  float s = 0.f;
  for (int c = 0; c < C; ++c){ float v = r[c]; s += v*v; }
  out[t] = s;
}
__global__ void norms_hl_kernel(const __hip_bfloat16* __restrict__ Xh, const __hip_bfloat16* __restrict__ Xl,
                                int ld, int C, float* __restrict__ out){
  int t = blockIdx.x*256 + threadIdx.x;
  if (t >= Mm) return;
  size_t base = (size_t)t*ld;
  float s = 0.f;
  for (int c = 0; c < C; ++c){
    float v = __bfloat162float(Xh[base+c]) + __bfloat162float(Xl[base+c]);
    s += v*v;
  }
  out[t] = s;
}

// ---------- MFMA KNN: wave owns 16 queries; 3-pass bf16 hi/lo distances ----------
template<int C>
__global__ __launch_bounds__(256, 4) void knn_mfma_kernel(
    const __hip_bfloat16* __restrict__ Xh, const __hip_bfloat16* __restrict__ Xl, int lda,
    const float* __restrict__ n2,
    float* __restrict__ outd, int* __restrict__ outi)
{
  constexpr int KS = C/32;
  __shared__ float Dt[4][16*17];
  const int tid = threadIdx.x;
  const int lane = tid & 63;
  const int w = tid >> 6;
  const int b = blockIdx.z, bN = b*Nn;
  const int q0 = blockIdx.x*64 + w*16;
  const int g = blockIdx.y;
  const int kq = (lane >> 4) * 8;

  bf16x8 Ah[KS], Al[KS];
  {
    const size_t qrow = (size_t)(bN + q0 + (lane & 15))*lda;
    #pragma unroll
    for (int s = 0; s < KS; ++s){
      Ah[s] = *reinterpret_cast<const bf16x8*>(Xh + qrow + s*32 + kq);
      Al[s] = *reinterpret_cast<const bf16x8*>(Xl + qrow + s*32 + kq);
    }
  }

  float bd[20]; int bi[20];
  #pragma unroll
  for (int l = 0; l < 20; ++l){ bd[l] = 1e30f; bi[l] = 0x7fffffff; }
  float worst = 1e30f; int wp = 0;

  const int NT = (Nn/Gg)/16;
  float* dtw = Dt[w];
  for (int jt = 0; jt < NT; ++jt){
    const int j0 = g*(Nn/Gg) + jt*16;
    const size_t crow = (size_t)(bN + j0 + (lane & 15))*lda;
    f32x4 acc = {0.f, 0.f, 0.f, 0.f};
    #pragma unroll
    for (int s = 0; s < KS; ++s){
      bf16x8 Bh = *reinterpret_cast<const bf16x8*>(Xh + crow + s*32 + kq);
      bf16x8 Bl = *reinterpret_cast<const bf16x8*>(Xl + crow + s*32 + kq);
      acc = __builtin_amdgcn_mfma_f32_16x16x32_bf16(Ah[s], Bh, acc, 0, 0, 0);
      acc = __builtin_amdgcn_mfma_f32_16x16x32_bf16(Ah[s], Bl, acc, 0, 0, 0);
      acc = __builtin_amdgcn_mfma_f32_16x16x32_bf16(Al[s], Bh, acc, 0, 0, 0);
    }
    float nj = n2[bN + j0 + (lane & 15)];
    const int rbase = (lane >> 4)*4;
    #pragma unroll
    for (int r = 0; r < 4; ++r)
      dtw[(rbase + r)*17 + (lane & 15)] = nj - 2.f*acc[r];
    const float* rowp = dtw + (lane >> 2)*17 + (lane & 3)*4;
    #pragma unroll
    for (int t = 0; t < 4; ++t){
      float d = rowp[t];
      if (d < worst){
        int j = j0 + (lane & 3)*4 + t;
        #pragma unroll
        for (int l = 0; l < 20; ++l) if (l == wp){ bd[l] = d; bi[l] = j; }
        worst = bd[0]; wp = 0;
        #pragma unroll
        for (int l = 1; l < 20; ++l) if (bd[l] > worst){ worst = bd[l]; wp = l; }
      }
    }
  }

  // merge each query's 4 partial lists via shfl; leader = lane%4==0
  float wd_ = bd[0]; int wi_ = bi[0]; int wp_ = 0;
  #pragma unroll
  for (int l = 1; l < 20; ++l)
    if (bd[l] > wd_ || (bd[l] == wd_ && bi[l] > wi_)){ wd_ = bd[l]; wi_ = bi[l]; wp_ = l; }
  const bool leader = (lane & 3) == 0;
  for (int p = 1; p < 4; ++p){
    #pragma unroll
    for (int l = 0; l < 20; ++l){
      float od = __shfl(bd[l], (lane & 60) + p, 64);
      int   oi = __shfl(bi[l], (lane & 60) + p, 64);
      bool better = leader && ((od < wd_) || (od == wd_ && oi < wi_));
      if (better){
        #pragma unroll
        for (int l2 = 0; l2 < 20; ++l2) if (l2 == wp_){ bd[l2] = od; bi[l2] = oi; }
        wd_ = bd[0]; wi_ = bi[0]; wp_ = 0;
        #pragma unroll
        for (int l2 = 1; l2 < 20; ++l2)
          if (bd[l2] > wd_ || (bd[l2] == wd_ && bi[l2] > wi_)){ wd_ = bd[l2]; wi_ = bi[l2]; wp_ = l2; }
      }
    }
  }
  if (leader){
    const int q = q0 + (lane >> 2);
    size_t base = ((size_t)(bN + q)*Gg + g)*20;
    #pragma unroll
    for (int l = 0; l < 20; ++l){ outd[base + l] = bd[l]; outi[base + l] = bi[l]; }
  }
}

// ---------- KNN for C=3 ----------
__global__ __launch_bounds__(256, 4) void knn3_kernel(
    const float* __restrict__ x, const float* __restrict__ n2,
    float* __restrict__ outd, int* __restrict__ outi)
{
  __shared__ __align__(16) float cs[512*4];
  const int tid = threadIdx.x;
  const int b = blockIdx.z, bN = b*Nn;
  const int g = blockIdx.y;                 // 0..7
  const int q = blockIdx.x*256 + tid;
  float qx = x[(size_t)(bN+q)*3 + 0];
  float qy = x[(size_t)(bN+q)*3 + 1];
  float qz = x[(size_t)(bN+q)*3 + 2];
  for (int e = tid; e < 512; e += 256){
    int j = g*512 + e;
    cs[e*4+0] = x[(size_t)(bN+j)*3 + 0];
    cs[e*4+1] = x[(size_t)(bN+j)*3 + 1];
    cs[e*4+2] = x[(size_t)(bN+j)*3 + 2];
    cs[e*4+3] = n2[bN+j];
  }
  __syncthreads();
  float bd[20]; int bi[20];
  #pragma unroll
  for (int l = 0; l < 20; ++l){ bd[l] = 1e30f; bi[l] = 0x7fffffff; }
  float worst = 1e30f; int wp = 0;
  for (int t = 0; t < 512; ++t){
    float4 c = *reinterpret_cast<const float4*>(&cs[t*4]);
    float d = c.w - 2.f*(qx*c.x + qy*c.y + qz*c.z);
    if (d < worst){
      int j = g*512 + t;
      #pragma unroll
      for (int l = 0; l < 20; ++l) if (l == wp){ bd[l] = d; bi[l] = j; }
      worst = bd[0]; wp = 0;
      #pragma unroll
      for (int l = 1; l < 20; ++l) if (bd[l] > worst){ worst = bd[l]; wp = l; }
    }
  }
  size_t base = ((size_t)(bN + q)*Gg + g)*20;
  #pragma unroll
  for (int l = 0; l < 20; ++l){ outd[base + l] = bd[l]; outi[base + l] = bi[l]; }
}

// ---------- final merge: G lists of 20 -> top-20 ----------
__global__ __launch_bounds__(256, 4) void knn_final_merge_kernel(
    const float* __restrict__ ind, const int* __restrict__ ini,
    int* __restrict__ idx)
{
  int t = blockIdx.x*256 + threadIdx.x;
  if (t >= Mm) return;
  size_t base = (size_t)t*Gg*20;
  float fd[20]; int fi[20];
  #pragma unroll
  for (int l = 0; l < 20; ++l){ fd[l] = 1e30f; fi[l] = 0x7fffffff; }
  float wd_ = 1e30f; int wi_ = 0x7fffffff; int wp_ = 0;
  for (int e = 0; e < Gg*20; ++e){
    float d = ind[base + e];
    int   id = ini[base + e];
    bool better = (d < wd_) || (d == wd_ && id < wi_);
    if (better){
      #pragma unroll
      for (int l = 0; l < 20; ++l) if (l == wp_){ fd[l] = d; fi[l] = id; }
      wd_ = fd[0]; wi_ = fi[0]; wp_ = 0;
      #pragma unroll
      for (int l = 1; l < 20; ++l)
        if (fd[l] > wd_ || (fd[l] == wd_ && fi[l] > wi_)){ wd_ = fd[l]; wi_ = fi[l]; wp_ = l; }
    }
  }
  #pragma unroll
  for (int l = 0; l < 20; ++l) idx[(size_t)t*Kk + l] = fi[l];
}

// ---------- gather-max epilogue: fp32 tb -> bf16 h/l activations ----------
__global__ void gathermax_kernel(const float* __restrict__ tb, const int* __restrict__ idx,
                                 const float* __restrict__ sv, const float* __restrict__ bv,
                                 int O, __hip_bfloat16* __restrict__ outh,
                                 __hip_bfloat16* __restrict__ outl, int ldo)
{
  int t = blockIdx.x*256 + threadIdx.x;
  int o = t % O;
  int m = t / O;           // b*N + i
  int b = m / Nn;
  const int twoO = 2*O;
  const int* ip = idx + (size_t)m*Kk;
  float mx = -1e30f;
  for (int j = 0; j < Kk; ++j){
    int jj = ip[j] & (Nn-1);
    mx = fmaxf(mx, tb[(size_t)(b*Nn + jj)*twoO + o]);
  }
  float basev = tb[(size_t)m*twoO + O + o];
  float y = lrelu_f((mx + basev) * sv[o] + bv[o]);
  __hip_bfloat16 h = __float2bfloat16(y);
  outh[(size_t)m*ldo + o] = h;
  outl[(size_t)m*ldo + o] = __float2bfloat16(y - __bfloat162float(h));
}

// ---------- ordered-uint float max keys ----------
__device__ __forceinline__ unsigned fkey(float f){
  unsigned u = __float_as_uint(f);
  return (u & 0x80000000u) ? ~u : (u | 0x80000000u);
}
__device__ __forceinline__ float funkey(unsigned k){
  if (k == 0u) return -1e30f;
  unsigned u = (k & 0x80000000u) ? (k ^ 0x80000000u) : ~k;
  return __uint_as_float(u);
}

// ---------- MFMA GEMM (LDS-staged): C[M,O] = (Ah+Al)[M,K] @ (Wh+Wl)[O,K]^T ----------
// 128x128 tile, BK=32, 4 waves x (64x64), hi/lo 3-pass
__global__ __launch_bounds__(256) void mfma_gemm_kernel(
    const __hip_bfloat16* __restrict__ Ah, const __hip_bfloat16* __restrict__ Al, int lda,
    const __hip_bfloat16* __restrict__ Wh, const __hip_bfloat16* __restrict__ Wl, int ldw,
    float* __restrict__ Cf, __hip_bfloat16* __restrict__ Ch, __hip_bfloat16* __restrict__ Cl, int ldc,
    int K, int O,
    const float* __restrict__ scale, const float* __restrict__ bias,
    const float* __restrict__ addvec, int lrelu_flag,
    unsigned* __restrict__ pool)
{
  constexpr int LDK = 40;   // bf16 elems per LDS row (32 + 8 pad -> 80B, 16B aligned)
  __shared__ __align__(16) __hip_bfloat16 AsH[128*LDK];
  __shared__ __align__(16) __hip_bfloat16 AsL[128*LDK];
  __shared__ __align__(16) __hip_bfloat16 BsH[128*LDK];
  __shared__ __align__(16) __hip_bfloat16 BsL[128*LDK];
  __shared__ float redp[2][128];
  const int tid = threadIdx.x;
  const int lane = tid & 63, w = tid >> 6;
  const int o0 = blockIdx.x*128, m0 = blockIdx.y*128;
  const int wr = (w >> 1)*64, wc = (w & 1)*64;
  const int kq = (lane >> 4)*8;
  const int fr = lane & 15;
  f32x4 acc[4][4] = {};

  for (int k0 = 0; k0 < K; k0 += 32){
    __syncthreads();
    #pragma unroll
    for (int j = 0; j < 2; ++j){
      int chunk = tid + j*256;
      int r = chunk >> 2, k8 = (chunk & 3)*8;
      size_t ga = (size_t)(m0 + r)*lda + k0 + k8;
      int oo = o0 + r; if (oo >= O) oo = O - 1;
      size_t gb = (size_t)oo*ldw + k0 + k8;
      int ls = r*LDK + k8;
      *reinterpret_cast<bf16x8*>(&AsH[ls]) = *reinterpret_cast<const bf16x8*>(Ah + ga);
      *reinterpret_cast<bf16x8*>(&AsL[ls]) = *reinterpret_cast<const bf16x8*>(Al + ga);
      *reinterpret_cast<bf16x8*>(&BsH[ls]) = *reinterpret_cast<const bf16x8*>(Wh + gb);
      *reinterpret_cast<bf16x8*>(&BsL[ls]) = *reinterpret_cast<const bf16x8*>(Wl + gb);
    }
    __syncthreads();
    bf16x8 ah[4], al[4];
    #pragma unroll
    for (int mi = 0; mi < 4; ++mi){
      int ls = (wr + mi*16 + fr)*LDK + kq;
      ah[mi] = *reinterpret_cast<const bf16x8*>(&AsH[ls]);
      al[mi] = *reinterpret_cast<const bf16x8*>(&AsL[ls]);
    }
    #pragma unroll
    for (int ni = 0; ni < 4; ++ni){
      int ls = (wc + ni*16 + fr)*LDK + kq;
      bf16x8 bh = *reinterpret_cast<const bf16x8*>(&BsH[ls]);
      bf16x8 bl = *reinterpret_cast<const bf16x8*>(&BsL[ls]);
      #pragma unroll
      for (int mi = 0; mi < 4; ++mi){
        acc[mi][ni] = __builtin_amdgcn_mfma_f32_16x16x32_bf16(ah[mi], bh, acc[mi][ni], 0, 0, 0);
        acc[mi][ni] = __builtin_amdgcn_mfma_f32_16x16x32_bf16(ah[mi], bl, acc[mi][ni], 0, 0, 0);
        acc[mi][ni] = __builtin_amdgcn_mfma_f32_16x16x32_bf16(al[mi], bh, acc[mi][ni], 0, 0, 0);
      }
    }
  }
  const int b = m0 / Nn;
  if (pool){
    #pragma unroll
    for (int ni = 0; ni < 4; ++ni){
      int o = o0 + wc + ni*16 + fr;
      float sc_ = scale[o], bi_ = bias[o];
      float m = -1e30f;
      #pragma unroll
      for (int mi = 0; mi < 4; ++mi)
        #pragma unroll
        for (int r = 0; r < 4; ++r)
          m = fmaxf(m, lrelu_f(acc[mi][ni][r]*sc_ + bi_));
      m = fmaxf(m, __shfl_xor(m, 16, 64));
      m = fmaxf(m, __shfl_xor(m, 32, 64));
      if ((lane >> 4) == 0) redp[w >> 1][wc + ni*16 + fr] = m;
    }
    __syncthreads();
    if (tid < 128){
      float m = fmaxf(redp[0][tid], redp[1][tid]);
      atomicMax(&pool[b*O + o0 + tid], fkey(m));
    }
    return;
  }
  #pragma unroll
  for (int ni = 0; ni < 4; ++ni){
    int o = o0 + wc + ni*16 + fr;
    if (o >= O) continue;
    float sc_ = scale ? scale[o] : 1.f;
    float bi_ = bias ? bias[o] : 0.f;
    float av  = addvec ? addvec[b*O + o] : 0.f;
    #pragma unroll
    for (int mi = 0; mi < 4; ++mi){
      #pragma unroll
      for (int r = 0; r < 4; ++r){
        int m = m0 + wr + mi*16 + (lane >> 4)*4 + r;
        float y = acc[mi][ni][r] + av;
        if (scale) y = y*sc_ + bi_;
        else       y = y + bi_;
        if (lrelu_flag) y = lrelu_f(y);
        if (Ch){
          __hip_bfloat16 h = __float2bfloat16(y);
          Ch[(size_t)m*ldc + o] = h;
          Cl[(size_t)m*ldc + o] = __float2bfloat16(y - __bfloat162float(h));
        } else {
          Cf[(size_t)m*ldc + o] = y;
        }
      }
    }
  }
}

// ---------- fp32 GEMM (layer-1 tb only, K=3) ----------
__global__ __launch_bounds__(256) void gemm_kernel(
    const float* __restrict__ A, int lda,
    const float* __restrict__ W, int ldw,
    float* __restrict__ Cf, int ldc, int K, int O)
{
  const int tid = threadIdx.x;
  const int tx = tid & 15, ty = tid >> 4;
  const int m0 = blockIdx.y * 64;
  const int o0 = blockIdx.x * 64;
  __shared__ __align__(16) float As[16*68];
  __shared__ __align__(16) float Ws[16*68];
  float acc[4][4] = {};
  for (int k0 = 0; k0 < K; k0 += 16){
    __syncthreads();
    #pragma unroll
    for (int r = 0; r < 4; ++r){
      int e = tid + r*256;
      int k = e & 15, mi = e >> 4;
      int kk = k0 + k;
      float v = 0.f, wv = 0.f;
      if (kk < K) v = A[(size_t)(m0+mi)*lda + kk];
      int oo = o0 + mi;
      if (kk < K && oo < O) wv = W[(size_t)oo*ldw + kk];
      As[k*68 + mi] = v;
      Ws[k*68 + mi] = wv;
    }
    __syncthreads();
    #pragma unroll
    for (int kk = 0; kk < 16; ++kk){
      float4 av = *reinterpret_cast<const float4*>(&As[kk*68 + ty*4]);
      float4 wv = *reinterpret_cast<const float4*>(&Ws[kk*68 + tx*4]);
      float a4[4] = {av.x, av.y, av.z, av.w};
      float w4[4] = {wv.x, wv.y, wv.z, wv.w};
      #pragma unroll
      for (int i = 0; i < 4; ++i)
        #pragma unroll
        for (int j = 0; j < 4; ++j)
          acc[i][j] += a4[i]*w4[j];
    }
  }
  #pragma unroll
  for (int i = 0; i < 4; ++i){
    int m = m0 + ty*4 + i;
    #pragma unroll
    for (int j = 0; j < 4; ++j){
      int o = o0 + tx*4 + j;
      if (o >= O) continue;
      Cf[(size_t)m*ldc + o] = acc[i][j];
    }
  }
}

// gvec[b,o2] = sum_c wh1[o2, 512+c] * glob[b,c]  (one wave per (b,o2))
__global__ void gvec_kernel(const __hip_bfloat16* __restrict__ Wh, const __hip_bfloat16* __restrict__ Wl,
                            const unsigned* __restrict__ glob, float* __restrict__ gv){
  int lane = threadIdx.x & 63, w = threadIdx.x >> 6;
  int o2 = blockIdx.x*4 + w;
  int b = blockIdx.y;
  size_t base = (size_t)o2*1536 + 512;
  float s = 0.f;
  for (int c = lane; c < 1024; c += 64){
    float wv = __bfloat162float(Wh[base+c]) + __bfloat162float(Wl[base+c]);
    s += wv * funkey(glob[b*1024 + c]);
  }
  #pragma unroll
  for (int off = 32; off >= 1; off >>= 1) s += __shfl_xor(s, off, 64);
  if (lane == 0) gv[b*256 + o2] = s;
}

// ---------- flag-gated output store ----------
__global__ void store_out_kernel(const float* __restrict__ src, const int* __restrict__ flag,
                                 void* __restrict__ dst, int n){
  int t = blockIdx.x*256 + threadIdx.x;
  if (t >= n) return;
  float v = src[t];
  if (*flag) ((__hip_bfloat16*)dst)[t] = __float2bfloat16(v);
  else       ((float*)dst)[t] = v;
}

extern "C" void kernel_launch(void* const* d_in, const int* in_sizes, int n_in,
                              void* d_out, int out_size, void* d_ws, size_t ws_size,
                              hipStream_t stream) {
  (void)in_sizes; (void)n_in; (void)out_size; (void)ws_size;
  float* ws = (float*)d_ws;
  int* dflag = (int*)(ws + O_DFLAG);
  float* xyzf = ws + O_XYZ;
  float* nrm  = ws + O_NRM;
  int*   idx  = (int*)(ws + O_IDX);
  unsigned* glob = (unsigned*)(ws + O_GLOB);
  float* gv = ws + O_GV;
  __hip_bfloat16* WBH = (__hip_bfloat16*)(ws + O_WBH);
  __hip_bfloat16* WBL = (__hip_bfloat16*)(ws + O_WBL);
  __hip_bfloat16* WCH = (__hip_bfloat16*)(ws + O_WCATH);
  __hip_bfloat16* WCL = (__hip_bfloat16*)(ws + O_WCATL);
  __hip_bfloat16* XCH = (__hip_bfloat16*)(ws + O_XCATH);
  __hip_bfloat16* XCL = (__hip_bfloat16*)(ws + O_XCATL);
  float* regB = ws + O_REGB;
  float* dpart = regB;
  int*   ipart = (int*)(regB + (size_t)Mm*Gg*20);
  float* tb    = regB;
  __hip_bfloat16* XLH = (__hip_bfloat16*)regB;
  __hip_bfloat16* XLL = (__hip_bfloat16*)(regB + 4194304);
  float* logitsF = regB;
  __hip_bfloat16* H1H = (__hip_bfloat16*)(ws + O_H1H);
  __hip_bfloat16* H1L = (__hip_bfloat16*)(ws + O_H1L);
  __hip_bfloat16* H2H = (__hip_bfloat16*)(ws + O_H2H);
  __hip_bfloat16* H2L = (__hip_bfloat16*)(ws + O_H2L);

  // ---- detect + fused conversions ----
  detect_kernel<<<1, 256, 0, stream>>>(d_in[0], Mm*3, dflag);
  cvt_small_kernel<<<(49152+4096+5200+255)/256, 256, 0, stream>>>(ws, dflag,
      d_in[0], d_in[3], d_in[4], d_in[6], d_in[7], d_in[9], d_in[10], d_in[12], d_in[13],
      d_in[15], d_in[16], d_in[18], d_in[19], d_in[21], d_in[22], d_in[24], d_in[25], d_in[27]);
  cvt_w_kernel<<<(WTOT+255)/256, 256, 0, stream>>>(ws, dflag,
      d_in[14], d_in[17], d_in[20], d_in[23], d_in[26]);

  auto mgemm = [&](const __hip_bfloat16* Ah, const __hip_bfloat16* Al, int lda,
                   const __hip_bfloat16* Wh, const __hip_bfloat16* Wl, int ldw,
                   float* Cf, __hip_bfloat16* Ch, __hip_bfloat16* Cl, int ldc,
                   int K, int O, const float* sc, const float* bi, const float* av,
                   int lr, unsigned* pool){
    dim3 g((O+127)/128, Mm/128);
    mfma_gemm_kernel<<<g, 256, 0, stream>>>(Ah, Al, lda, Wh, Wl, ldw, Cf, Ch, Cl, ldc,
                                            K, O, sc, bi, av, lr, pool);
  };

  // ---- edgeconv layer 1 (C=3) ----
  norms_kernel<<<Mm/256, 256, 0, stream>>>(xyzf, 3, 3, nrm);
  knn3_kernel<<<dim3(Nn/256, Gg, Bb), 256, 0, stream>>>(xyzf, nrm, dpart, ipart);
  knn_final_merge_kernel<<<Mm/256, 256, 0, stream>>>(dpart, ipart, idx);
  prep_w1_kernel<<<1, 256, 0, stream>>>(ws, dflag, d_in[2]);
  gemm_kernel<<<dim3(2, Mm/64), 256, 0, stream>>>(xyzf, 3, ws + O_WCAT1, 3, tb, 128, 3, 128);
  gathermax_kernel<<<((size_t)Mm*64)/256, 256, 0, stream>>>(
      tb, idx, ws+O_S1, ws+O_B1, 64, XCH + 0, XCL + 0, 512);

  // ---- edgeconv layers 2-4 (MFMA path) ----
  struct LayerDef { int coff; int C; int O; size_t so, bo; int win; };
  LayerDef L[3] = {
    {0,   64, 64,  O_S2, O_B2, 5},
    {64,  64, 128, O_S3, O_B3, 8},
    {128, 128, 256, O_S4, O_B4, 11},
  };
  for (int li = 0; li < 3; ++li){
    int C = L[li].C, O = L[li].O, coff = L[li].coff;
    norms_hl_kernel<<<Mm/256, 256, 0, stream>>>(XCH + coff, XCL + coff, 512, C, nrm);
    if (C == 64)
      knn_mfma_kernel<64><<<dim3(Nn/64, Gg, Bb), 256, 0, stream>>>(XCH + coff, XCL + coff, 512, nrm, dpart, ipart);
    else
      knn_mfma_kernel<128><<<dim3(Nn/64, Gg, Bb), 256, 0, stream>>>(XCH + coff, XCL + coff, 512, nrm, dpart, ipart);
    knn_final_merge_kernel<<<Mm/256, 256, 0, stream>>>(dpart, ipart, idx);
    prep_w_hl_kernel<<<(O*C+255)/256, 256, 0, stream>>>(ws, dflag, d_in[L[li].win], C, O);
    mgemm(XCH + coff, XCL + coff, 512, WCH, WCL, C, tb, nullptr, nullptr, 2*O, C, 2*O,
          nullptr, nullptr, nullptr, 0, nullptr);
    gathermax_kernel<<<((size_t)Mm*O)/256, 256, 0, stream>>>(
        tb, idx, ws + L[li].so, ws + L[li].bo, O, XCH + coff + C, XCL + coff + C, 512);
  }

  // ---- chain ----
  mgemm(XCH, XCL, 512, WBH + WOF_WF, WBL + WOF_WF, 512, nullptr, XLH, XLL, 512,
        512, 512, ws+O_SF, ws+O_BF, nullptr, 1, nullptr);
  mgemm(XLH, XLL, 512, WBH + WOF_WE, WBL + WOF_WE, 512, nullptr, nullptr, nullptr, 0,
        512, 1024, ws+O_SE, ws+O_BE, nullptr, 1, glob);
  gvec_kernel<<<dim3(64, Bb), 256, 0, stream>>>(WBH + WOF_WH1, WBL + WOF_WH1, glob, gv);
  mgemm(XLH, XLL, 512, WBH + WOF_WH1, WBL + WOF_WH1, 1536, nullptr, H1H, H1L, 256,
        512, 256, ws+O_SH1, ws+O_BH1, gv, 1, nullptr);
  mgemm(H1H, H1L, 256, WBH + WOF_WH2, WBL + WOF_WH2, 256, nullptr, H2H, H2L, 256,
        256, 256, ws+O_SH2, ws+O_BH2, nullptr, 1, nullptr);
  mgemm(H2H, H2L, 256, WBH + WOF_WH3, WBL + WOF_WH3, 256, logitsF, nullptr, nullptr, 50,
        256, 50, nullptr, ws+O_BH3, nullptr, 0, nullptr);
  store_out_kernel<<<((size_t)Mm*50 + 255)/256, 256, 0, stream>>>(logitsF, dflag, d_out, Mm*50);
}

// Round 11
// 2379.313 us; speedup vs baseline: 1.3766x; 1.2413x over previous
//
#include <hip/hip_runtime.h>
#include <hip/hip_bf16.h>
#include <cstdint>

#define LEAKV 0.2f
static const int Bb = 4, Nn = 4096, Mm = 16384, Kk = 20;
static const int Gg = 8;

typedef __attribute__((ext_vector_type(8))) short bf16x8;
typedef __attribute__((ext_vector_type(4))) float f32x4;
typedef unsigned long long u64;

__device__ __forceinline__ float lrelu_f(float v){ return v > 0.f ? v : LEAKV*v; }

// ---------------- workspace layout (float offsets, compile-time) ----------------
constexpr size_t O_DFLAG = 0;
constexpr size_t O_XYZ   = 16;
constexpr size_t O_NRM   = 49168;
constexpr size_t O_IDX   = 65552;
constexpr size_t O_GLOB  = 393232;
constexpr size_t O_GV    = 397328;
constexpr size_t O_S1 = 398352, O_B1 = 398416, O_S2 = 398480, O_B2 = 398544;
constexpr size_t O_S3 = 398608, O_B3 = 398736, O_S4 = 398864, O_B4 = 399120;
constexpr size_t O_SF = 399376, O_BF = 399888, O_SE = 400400, O_BE = 401424;
constexpr size_t O_SH1 = 402448, O_BH1 = 402704, O_SH2 = 402960, O_BH2 = 403216;
constexpr size_t O_BH3 = 403472;
constexpr size_t O_WCAT1 = 403536;
constexpr size_t O_WBH  = 404992;
constexpr size_t O_WBL  = 1033984;
constexpr size_t O_WCATH = 1662976;
constexpr size_t O_WCATL = 1695744;
constexpr size_t O_XCATH = 1728512;
constexpr size_t O_XCATL = 5922816;
constexpr size_t O_REGB  = 10117120;
constexpr size_t O_H1H = O_XCATH;
constexpr size_t O_H1L = O_XCATH + 2097152;
constexpr size_t O_H2H = O_XCATH + 4194304;
constexpr size_t O_H2L = O_XCATH + 6291456;
constexpr size_t WOF_WF = 0, WOF_WE = 262144, WOF_WH1 = 786432, WOF_WH2 = 1179648, WOF_WH3 = 1245184;
constexpr int WTOT = 1257984;

// ---------- dtype detector ----------
__global__ void detect_kernel(const void* __restrict__ xyz, int n, int* __restrict__ flag){
  __shared__ int cnt;
  if (threadIdx.x == 0) cnt = 0;
  __syncthreads();
  const __hip_bfloat16* p = (const __hip_bfloat16*)xyz;
  int local = 0;
  for (int i = threadIdx.x; i < n; i += 256){
    float v = __bfloat162float(p[i]);
    if (!(fabsf(v) < 1000.f)) local++;
  }
  atomicAdd(&cnt, local);
  __syncthreads();
  if (threadIdx.x == 0) *flag = (cnt < n/16) ? 1 : 0;   // 1 = bf16, 0 = fp32
}

__device__ __forceinline__ float rdval(const void* p, int i, int flag){
  return flag ? __bfloat162float(((const __hip_bfloat16*)p)[i]) : ((const float*)p)[i];
}

// ---------- fused small-input conversion + glob init ----------
__global__ void cvt_small_kernel(float* __restrict__ ws, const int* __restrict__ flag,
    const void* xyz, const void* s1, const void* b1, const void* s2, const void* b2,
    const void* s3, const void* b3, const void* s4, const void* b4,
    const void* sf, const void* bf, const void* se, const void* be,
    const void* sh1, const void* bh1, const void* sh2, const void* bh2, const void* bh3)
{
  int t = blockIdx.x*256 + threadIdx.x;
  int fl = *flag;
  if (t < 49152){ ws[O_XYZ + t] = rdval(xyz, t, fl); return; }
  t -= 49152;
  if (t < 4096){ ((unsigned*)(ws + O_GLOB))[t] = 0u; return; }
  t -= 4096;
  if (t < 64){ ws[O_S1+t] = rdval(s1,t,fl); return; }  t -= 64;
  if (t < 64){ ws[O_B1+t] = rdval(b1,t,fl); return; }  t -= 64;
  if (t < 64){ ws[O_S2+t] = rdval(s2,t,fl); return; }  t -= 64;
  if (t < 64){ ws[O_B2+t] = rdval(b2,t,fl); return; }  t -= 64;
  if (t < 128){ ws[O_S3+t] = rdval(s3,t,fl); return; } t -= 128;
  if (t < 128){ ws[O_B3+t] = rdval(b3,t,fl); return; } t -= 128;
  if (t < 256){ ws[O_S4+t] = rdval(s4,t,fl); return; } t -= 256;
  if (t < 256){ ws[O_B4+t] = rdval(b4,t,fl); return; } t -= 256;
  if (t < 512){ ws[O_SF+t] = rdval(sf,t,fl); return; } t -= 512;
  if (t < 512){ ws[O_BF+t] = rdval(bf,t,fl); return; } t -= 512;
  if (t < 1024){ ws[O_SE+t] = rdval(se,t,fl); return; } t -= 1024;
  if (t < 1024){ ws[O_BE+t] = rdval(be,t,fl); return; } t -= 1024;
  if (t < 256){ ws[O_SH1+t] = rdval(sh1,t,fl); return; } t -= 256;
  if (t < 256){ ws[O_BH1+t] = rdval(bh1,t,fl); return; } t -= 256;
  if (t < 256){ ws[O_SH2+t] = rdval(sh2,t,fl); return; } t -= 256;
  if (t < 256){ ws[O_BH2+t] = rdval(bh2,t,fl); return; } t -= 256;
  if (t < 50){ ws[O_BH3+t] = rdval(bh3,t,fl); return; }
}

// ---------- fused big-weight conversion -> bf16 hi/lo ----------
__global__ void cvt_w_kernel(float* __restrict__ ws, const int* __restrict__ flag,
    const void* wf, const void* we, const void* wh1, const void* wh2, const void* wh3)
{
  int t = blockIdx.x*256 + threadIdx.x;
  if (t >= WTOT) return;
  int fl = *flag;
  float v;
  if (t < (int)WOF_WE)        v = rdval(wf,  t, fl);
  else if (t < (int)WOF_WH1)  v = rdval(we,  t - WOF_WE, fl);
  else if (t < (int)WOF_WH2)  v = rdval(wh1, t - WOF_WH1, fl);
  else if (t < (int)WOF_WH3)  v = rdval(wh2, t - WOF_WH2, fl);
  else                        v = rdval(wh3, t - WOF_WH3, fl);
  __hip_bfloat16 h = __float2bfloat16(v);
  ((__hip_bfloat16*)(ws + O_WBH))[t] = h;
  ((__hip_bfloat16*)(ws + O_WBL))[t] = __float2bfloat16(v - __bfloat162float(h));
}

// ---------- edgeconv weight prep: wcat = [w_d ; w_x - w_d] -> bf16 h/l ----------
__global__ void prep_w_hl_kernel(float* __restrict__ ws, const int* __restrict__ flag,
                                 const void* __restrict__ w, int C, int O){
  int t = blockIdx.x*256 + threadIdx.x;
  if (t >= O*C) return;
  int fl = *flag;
  int o = t / C, c = t - o*C;
  float wd = rdval(w, o*2*C + c, fl);
  float wx = rdval(w, o*2*C + C + c, fl);
  float dx = wx - wd;
  __hip_bfloat16* Wh = (__hip_bfloat16*)(ws + O_WCATH);
  __hip_bfloat16* Wl = (__hip_bfloat16*)(ws + O_WCATL);
  __hip_bfloat16 h1 = __float2bfloat16(wd);
  Wh[o*C + c] = h1; Wl[o*C + c] = __float2bfloat16(wd - __bfloat162float(h1));
  __hip_bfloat16 h2 = __float2bfloat16(dx);
  Wh[(O+o)*C + c] = h2; Wl[(O+o)*C + c] = __float2bfloat16(dx - __bfloat162float(h2));
}

// layer-1 fp32 wcat [128][3]
__global__ void prep_w1_kernel(float* __restrict__ ws, const int* __restrict__ flag,
                               const void* __restrict__ w){
  int t = blockIdx.x*256 + threadIdx.x;
  if (t >= 64*3) return;
  int fl = *flag;
  int o = t / 3, c = t - o*3;
  float wd = rdval(w, o*6 + c, fl);
  float wx = rdval(w, o*6 + 3 + c, fl);
  ws[O_WCAT1 + o*3 + c] = wd;
  ws[O_WCAT1 + (64+o)*3 + c] = wx - wd;
}

// ---------- norms ----------
__global__ void norms_kernel(const float* __restrict__ x, int ld, int C, float* __restrict__ out){
  int t = blockIdx.x*256 + threadIdx.x;
  if (t >= Mm) return;
  const float* r = x + (size_t)t*ld;
  float s = 0.f;
  for (int c = 0; c < C; ++c){ float v = r[c]; s += v*v; }
  out[t] = s;
}
__global__ void norms_hl_kernel(const __hip_bfloat16* __restrict__ Xh, const __hip_bfloat16* __restrict__ Xl,
                                int ld, int C, float* __restrict__ out){
  int t = blockIdx.x*256 + threadIdx.x;
  if (t >= Mm) return;
  size_t base = (size_t)t*ld;
  float s = 0.f;
  for (int c = 0; c < C; ++c){
    float v = __bfloat162float(Xh[base+c]) + __bfloat162float(Xl[base+c]);
    s += v*v;
  }
  out[t] = s;
}

__device__ __forceinline__ unsigned fkey(float f){
  unsigned u = __float_as_uint(f);
  return (u & 0x80000000u) ? ~u : (u | 0x80000000u);
}
__device__ __forceinline__ float funkey(unsigned k){
  if (k == 0u) return -1e30f;
  unsigned u = (k & 0x80000000u) ? (k ^ 0x80000000u) : ~k;
  return __uint_as_float(u);
}
// sorted-descending packed top-20 insert (kd[0] = worst)
__device__ __forceinline__ void kinsert(u64 (&kd)[20], u64 key){
  kd[0] = key;
  #pragma unroll
  for (int l = 0; l < 19; ++l){
    bool s = kd[l] < kd[l+1];
    u64 a = s ? kd[l+1] : kd[l];
    u64 b = s ? kd[l]   : kd[l+1];
    kd[l] = a; kd[l+1] = b;
  }
}

// ---------- MFMA KNN: wave owns 16 queries; packed-u64 sorted selection ----------
template<int C>
__global__ __launch_bounds__(256, 4) void knn_mfma_kernel(
    const __hip_bfloat16* __restrict__ Xh, const __hip_bfloat16* __restrict__ Xl, int lda,
    const float* __restrict__ n2,
    u64* __restrict__ kpart)
{
  constexpr int KS = C/32;
  // per-wave 10240B slab: first 1088B doubles as Dt[16][17] during scan,
  // whole slab becomes the u64 merge buffer [64][20] afterwards (same-wave only -> no race)
  __shared__ __align__(16) char smem[40960];
  const int tid = threadIdx.x;
  const int lane = tid & 63;
  const int w = tid >> 6;
  const int b = blockIdx.z, bN = b*Nn;
  const int q0 = blockIdx.x*64 + w*16;
  const int g = blockIdx.y;
  const int kq = (lane >> 4) * 8;
  float* dtw = (float*)(smem + w*10240);
  u64* sm64 = (u64*)(smem + w*10240);

  bf16x8 Ah[KS], Al[KS];
  {
    const size_t qrow = (size_t)(bN + q0 + (lane & 15))*lda;
    #pragma unroll
    for (int s = 0; s < KS; ++s){
      Ah[s] = *reinterpret_cast<const bf16x8*>(Xh + qrow + s*32 + kq);
      Al[s] = *reinterpret_cast<const bf16x8*>(Xl + qrow + s*32 + kq);
    }
  }

  u64 kd[20];
  #pragma unroll
  for (int l = 0; l < 20; ++l) kd[l] = ~0ULL;

  const int NT = (Nn/Gg)/16;
  for (int jt = 0; jt < NT; ++jt){
    const int j0 = g*(Nn/Gg) + jt*16;
    const size_t crow = (size_t)(bN + j0 + (lane & 15))*lda;
    f32x4 acc = {0.f, 0.f, 0.f, 0.f};
    #pragma unroll
    for (int s = 0; s < KS; ++s){
      bf16x8 Bh = *reinterpret_cast<const bf16x8*>(Xh + crow + s*32 + kq);
      bf16x8 Bl = *reinterpret_cast<const bf16x8*>(Xl + crow + s*32 + kq);
      acc = __builtin_amdgcn_mfma_f32_16x16x32_bf16(Ah[s], Bh, acc, 0, 0, 0);
      acc = __builtin_amdgcn_mfma_f32_16x16x32_bf16(Ah[s], Bl, acc, 0, 0, 0);
      acc = __builtin_amdgcn_mfma_f32_16x16x32_bf16(Al[s], Bh, acc, 0, 0, 0);
    }
    float nj = n2[bN + j0 + (lane & 15)];
    const int rbase = (lane >> 4)*4;
    #pragma unroll
    for (int r = 0; r < 4; ++r)
      dtw[(rbase + r)*17 + (lane & 15)] = nj - 2.f*acc[r];
    const float* rowp = dtw + (lane >> 2)*17 + (lane & 3)*4;
    #pragma unroll
    for (int t = 0; t < 4; ++t){
      float d = rowp[t];
      u64 key = ((u64)fkey(d) << 32) | (unsigned)(j0 + (lane & 3)*4 + t);
      if (key < kd[0]) kinsert(kd, key);
    }
  }

  // dump sorted (descending) list to the wave's LDS slab
  #pragma unroll
  for (int l = 0; l < 20; ++l) sm64[lane*20 + l] = kd[l];
  // quad leader: 4-way merge of ascending streams (pop from tail)
  if ((lane & 3) == 0){
    unsigned hpack = 0x13131313u;   // four 8-bit heads = 19
    u64 v0 = sm64[(lane+0)*20 + 19];
    u64 v1 = sm64[(lane+1)*20 + 19];
    u64 v2 = sm64[(lane+2)*20 + 19];
    u64 v3 = sm64[(lane+3)*20 + 19];
    const int q = q0 + (lane >> 2);
    u64* outp = kpart + ((size_t)(bN + q)*Gg + g)*20;
    #pragma unroll
    for (int r = 0; r < 20; ++r){
      u64 m01 = v0 < v1 ? v0 : v1; int p01 = v0 < v1 ? 0 : 1;
      u64 m23 = v2 < v3 ? v2 : v3; int p23 = v2 < v3 ? 2 : 3;
      bool f01 = m01 < m23;
      u64 mv = f01 ? m01 : m23;
      int mp = f01 ? p01 : p23;
      outp[r] = mv;
      int sh = mp*8;
      int h = (int)((hpack >> sh) & 0xffu) - 1;
      hpack -= (1u << sh);
      int hc = h < 0 ? 0 : h;
      u64 rv = sm64[(lane + mp)*20 + hc];
      u64 nv = (h >= 0) ? rv : ~0ULL;
      v0 = (mp == 0) ? nv : v0;
      v1 = (mp == 1) ? nv : v1;
      v2 = (mp == 2) ? nv : v2;
      v3 = (mp == 3) ? nv : v3;
    }
  }
}

// ---------- KNN for C=3: packed-u64 sorted selection ----------
__global__ __launch_bounds__(256, 4) void knn3_kernel(
    const float* __restrict__ x, const float* __restrict__ n2,
    u64* __restrict__ kpart)
{
  __shared__ __align__(16) float cs[512*4];
  const int tid = threadIdx.x;
  const int b = blockIdx.z, bN = b*Nn;
  const int g = blockIdx.y;                 // 0..7
  const int q = blockIdx.x*256 + tid;
  float qx = x[(size_t)(bN+q)*3 + 0];
  float qy = x[(size_t)(bN+q)*3 + 1];
  float qz = x[(size_t)(bN+q)*3 + 2];
  for (int e = tid; e < 512; e += 256){
    int j = g*512 + e;
    cs[e*4+0] = x[(size_t)(bN+j)*3 + 0];
    cs[e*4+1] = x[(size_t)(bN+j)*3 + 1];
    cs[e*4+2] = x[(size_t)(bN+j)*3 + 2];
    cs[e*4+3] = n2[bN+j];
  }
  __syncthreads();
  u64 kd[20];
  #pragma unroll
  for (int l = 0; l < 20; ++l) kd[l] = ~0ULL;
  for (int t = 0; t < 512; ++t){
    float4 c = *reinterpret_cast<const float4*>(&cs[t*4]);
    float d = c.w - 2.f*(qx*c.x + qy*c.y + qz*c.z);
    u64 key = ((u64)fkey(d) << 32) | (unsigned)(g*512 + t);
    if (key < kd[0]) kinsert(kd, key);
  }
  u64* outp = kpart + ((size_t)(bN + q)*Gg + g)*20;
  #pragma unroll
  for (int l = 0; l < 20; ++l) outp[l] = kd[19-l];   // ascending
}

// ---------- final merge: Gg sorted ascending 20-lists -> top-20 ----------
__global__ __launch_bounds__(256, 4) void knn_final_merge_kernel(
    const u64* __restrict__ kpart, int* __restrict__ idx)
{
  int t = blockIdx.x*256 + threadIdx.x;
  if (t >= Mm) return;
  const u64* base = kpart + (size_t)t*Gg*20;
  u64 kd[20];
  #pragma unroll
  for (int l = 0; l < 20; ++l) kd[l] = ~0ULL;
  for (int g = 0; g < Gg; ++g){
    const u64* lp = base + g*20;
    #pragma unroll 1
    for (int l = 0; l < 20; ++l){
      u64 key = lp[l];
      if (key >= kd[0]) break;     // sorted -> rest are larger
      kinsert(kd, key);
    }
  }
  #pragma unroll
  for (int l = 0; l < 20; ++l) idx[(size_t)t*Kk + l] = (int)(kd[19-l] & 0xffffffffu);
}

// ---------- gather-max epilogue: fp32 tb -> bf16 h/l activations ----------
__global__ void gathermax_kernel(const float* __restrict__ tb, const int* __restrict__ idx,
                                 const float* __restrict__ sv, const float* __restrict__ bv,
                                 int O, __hip_bfloat16* __restrict__ outh,
                                 __hip_bfloat16* __restrict__ outl, int ldo)
{
  int t = blockIdx.x*256 + threadIdx.x;
  int o = t % O;
  int m = t / O;           // b*N + i
  int b = m / Nn;
  const int twoO = 2*O;
  const int* ip = idx + (size_t)m*Kk;
  float mx = -1e30f;
  for (int j = 0; j < Kk; ++j){
    int jj = ip[j] & (Nn-1);
    mx = fmaxf(mx, tb[(size_t)(b*Nn + jj)*twoO + o]);
  }
  float basev = tb[(size_t)m*twoO + O + o];
  float y = lrelu_f((mx + basev) * sv[o] + bv[o]);
  __hip_bfloat16 h = __float2bfloat16(y);
  outh[(size_t)m*ldo + o] = h;
  outl[(size_t)m*ldo + o] = __float2bfloat16(y - __bfloat162float(h));
}

// ---------- MFMA GEMM (LDS-staged): C[M,O] = (Ah+Al)[M,K] @ (Wh+Wl)[O,K]^T ----------
__global__ __launch_bounds__(256) void mfma_gemm_kernel(
    const __hip_bfloat16* __restrict__ Ah, const __hip_bfloat16* __restrict__ Al, int lda,
    const __hip_bfloat16* __restrict__ Wh, const __hip_bfloat16* __restrict__ Wl, int ldw,
    float* __restrict__ Cf, __hip_bfloat16* __restrict__ Ch, __hip_bfloat16* __restrict__ Cl, int ldc,
    int K, int O,
    const float* __restrict__ scale, const float* __restrict__ bias,
    const float* __restrict__ addvec, int lrelu_flag,
    unsigned* __restrict__ pool)
{
  constexpr int LDK = 40;
  __shared__ __align__(16) __hip_bfloat16 AsH[128*LDK];
  __shared__ __align__(16) __hip_bfloat16 AsL[128*LDK];
  __shared__ __align__(16) __hip_bfloat16 BsH[128*LDK];
  __shared__ __align__(16) __hip_bfloat16 BsL[128*LDK];
  __shared__ float redp[2][128];
  const int tid = threadIdx.x;
  const int lane = tid & 63, w = tid >> 6;
  const int o0 = blockIdx.x*128, m0 = blockIdx.y*128;
  const int wr = (w >> 1)*64, wc = (w & 1)*64;
  const int kq = (lane >> 4)*8;
  const int fr = lane & 15;
  f32x4 acc[4][4] = {};

  for (int k0 = 0; k0 < K; k0 += 32){
    __syncthreads();
    #pragma unroll
    for (int j = 0; j < 2; ++j){
      int chunk = tid + j*256;
      int r = chunk >> 2, k8 = (chunk & 3)*8;
      size_t ga = (size_t)(m0 + r)*lda + k0 + k8;
      int oo = o0 + r; if (oo >= O) oo = O - 1;
      size_t gb = (size_t)oo*ldw + k0 + k8;
      int ls = r*LDK + k8;
      *reinterpret_cast<bf16x8*>(&AsH[ls]) = *reinterpret_cast<const bf16x8*>(Ah + ga);
      *reinterpret_cast<bf16x8*>(&AsL[ls]) = *reinterpret_cast<const bf16x8*>(Al + ga);
      *reinterpret_cast<bf16x8*>(&BsH[ls]) = *reinterpret_cast<const bf16x8*>(Wh + gb);
      *reinterpret_cast<bf16x8*>(&BsL[ls]) = *reinterpret_cast<const bf16x8*>(Wl + gb);
    }
    __syncthreads();
    bf16x8 ah[4], al[4];
    #pragma unroll
    for (int mi = 0; mi < 4; ++mi){
      int ls = (wr + mi*16 + fr)*LDK + kq;
      ah[mi] = *reinterpret_cast<const bf16x8*>(&AsH[ls]);
      al[mi] = *reinterpret_cast<const bf16x8*>(&AsL[ls]);
    }
    #pragma unroll
    for (int ni = 0; ni < 4; ++ni){
      int ls = (wc + ni*16 + fr)*LDK + kq;
      bf16x8 bh = *reinterpret_cast<const bf16x8*>(&BsH[ls]);
      bf16x8 bl = *reinterpret_cast<const bf16x8*>(&BsL[ls]);
      #pragma unroll
      for (int mi = 0; mi < 4; ++mi){
        acc[mi][ni] = __builtin_amdgcn_mfma_f32_16x16x32_bf16(ah[mi], bh, acc[mi][ni], 0, 0, 0);
        acc[mi][ni] = __builtin_amdgcn_mfma_f32_16x16x32_bf16(ah[mi], bl, acc[mi][ni], 0, 0, 0);
        acc[mi][ni] = __builtin_amdgcn_mfma_f32_16x16x32_bf16(al[mi], bh, acc[mi][ni], 0, 0, 0);
      }
    }
  }
  const int b = m0 / Nn;
  if (pool){
    #pragma unroll
    for (int ni = 0; ni < 4; ++ni){
      int o = o0 + wc + ni*16 + fr;
      float sc_ = scale[o], bi_ = bias[o];
      float m = -1e30f;
      #pragma unroll
      for (int mi = 0; mi < 4; ++mi)
        #pragma unroll
        for (int r = 0; r < 4; ++r)
          m = fmaxf(m, lrelu_f(acc[mi][ni][r]*sc_ + bi_));
      m = fmaxf(m, __shfl_xor(m, 16, 64));
      m = fmaxf(m, __shfl_xor(m, 32, 64));
      if ((lane >> 4) == 0) redp[w >> 1][wc + ni*16 + fr] = m;
    }
    __syncthreads();
    if (tid < 128){
      float m = fmaxf(redp[0][tid], redp[1][tid]);
      atomicMax(&pool[b*O + o0 + tid], fkey(m));
    }
    return;
  }
  #pragma unroll
  for (int ni = 0; ni < 4; ++ni){
    int o = o0 + wc + ni*16 + fr;
    if (o >= O) continue;
    float sc_ = scale ? scale[o] : 1.f;
    float bi_ = bias ? bias[o] : 0.f;
    float av  = addvec ? addvec[b*O + o] : 0.f;
    #pragma unroll
    for (int mi = 0; mi < 4; ++mi){
      #pragma unroll
      for (int r = 0; r < 4; ++r){
        int m = m0 + wr + mi*16 + (lane >> 4)*4 + r;
        float y = acc[mi][ni][r] + av;
        if (scale) y = y*sc_ + bi_;
        else       y = y + bi_;
        if (lrelu_flag) y = lrelu_f(y);
        if (Ch){
          __hip_bfloat16 h = __float2bfloat16(y);
          Ch[(size_t)m*ldc + o] = h;
          Cl[(size_t)m*ldc + o] = __float2bfloat16(y - __bfloat162float(h));
        } else {
          Cf[(size_t)m*ldc + o] = y;
        }
      }
    }
  }
}

// ---------- fp32 GEMM (layer-1 tb only, K=3) ----------
__global__ __launch_bounds__(256) void gemm_kernel(
    const float* __restrict__ A, int lda,
    const float* __restrict__ W, int ldw,
    float* __restrict__ Cf, int ldc, int K, int O)
{
  const int tid = threadIdx.x;
  const int tx = tid & 15, ty = tid >> 4;
  const int m0 = blockIdx.y * 64;
  const int o0 = blockIdx.x * 64;
  __shared__ __align__(16) float As[16*68];
  __shared__ __align__(16) float Ws[16*68];
  float acc[4][4] = {};
  for (int k0 = 0; k0 < K; k0 += 16){
    __syncthreads();
    #pragma unroll
    for (int r = 0; r < 4; ++r){
      int e = tid + r*256;
      int k = e & 15, mi = e >> 4;
      int kk = k0 + k;
      float v = 0.f, wv = 0.f;
      if (kk < K) v = A[(size_t)(m0+mi)*lda + kk];
      int oo = o0 + mi;
      if (kk < K && oo < O) wv = W[(size_t)oo*ldw + kk];
      As[k*68 + mi] = v;
      Ws[k*68 + mi] = wv;
    }
    __syncthreads();
    #pragma unroll
    for (int kk = 0; kk < 16; ++kk){
      float4 av = *reinterpret_cast<const float4*>(&As[kk*68 + ty*4]);
      float4 wv = *reinterpret_cast<const float4*>(&Ws[kk*68 + tx*4]);
      float a4[4] = {av.x, av.y, av.z, av.w};
      float w4[4] = {wv.x, wv.y, wv.z, wv.w};
      #pragma unroll
      for (int i = 0; i < 4; ++i)
        #pragma unroll
        for (int j = 0; j < 4; ++j)
          acc[i][j] += a4[i]*w4[j];
    }
  }
  #pragma unroll
  for (int i = 0; i < 4; ++i){
    int m = m0 + ty*4 + i;
    #pragma unroll
    for (int j = 0; j < 4; ++j){
      int o = o0 + tx*4 + j;
      if (o >= O) continue;
      Cf[(size_t)m*ldc + o] = acc[i][j];
    }
  }
}

// gvec[b,o2] = sum_c wh1[o2, 512+c] * glob[b,c]
__global__ void gvec_kernel(const __hip_bfloat16* __restrict__ Wh, const __hip_bfloat16* __restrict__ Wl,
                            const unsigned* __restrict__ glob, float* __restrict__ gv){
  int lane = threadIdx.x & 63, w = threadIdx.x >> 6;
  int o2 = blockIdx.x*4 + w;
  int b = blockIdx.y;
  size_t base = (size_t)o2*1536 + 512;
  float s = 0.f;
  for (int c = lane; c < 1024; c += 64){
    float wv = __bfloat162float(Wh[base+c]) + __bfloat162float(Wl[base+c]);
    s += wv * funkey(glob[b*1024 + c]);
  }
  #pragma unroll
  for (int off = 32; off >= 1; off >>= 1) s += __shfl_xor(s, off, 64);
  if (lane == 0) gv[b*256 + o2] = s;
}

// ---------- flag-gated output store ----------
__global__ void store_out_kernel(const float* __restrict__ src, const int* __restrict__ flag,
                                 void* __restrict__ dst, int n){
  int t = blockIdx.x*256 + threadIdx.x;
  if (t >= n) return;
  float v = src[t];
  if (*flag) ((__hip_bfloat16*)dst)[t] = __float2bfloat16(v);
  else       ((float*)dst)[t] = v;
}

extern "C" void kernel_launch(void* const* d_in, const int* in_sizes, int n_in,
                              void* d_out, int out_size, void* d_ws, size_t ws_size,
                              hipStream_t stream) {
  (void)in_sizes; (void)n_in; (void)out_size; (void)ws_size;
  float* ws = (float*)d_ws;
  int* dflag = (int*)(ws + O_DFLAG);
  float* xyzf = ws + O_XYZ;
  float* nrm  = ws + O_NRM;
  int*   idx  = (int*)(ws + O_IDX);
  unsigned* glob = (unsigned*)(ws + O_GLOB);
  float* gv = ws + O_GV;
  __hip_bfloat16* WBH = (__hip_bfloat16*)(ws + O_WBH);
  __hip_bfloat16* WBL = (__hip_bfloat16*)(ws + O_WBL);
  __hip_bfloat16* WCH = (__hip_bfloat16*)(ws + O_WCATH);
  __hip_bfloat16* WCL = (__hip_bfloat16*)(ws + O_WCATL);
  __hip_bfloat16* XCH = (__hip_bfloat16*)(ws + O_XCATH);
  __hip_bfloat16* XCL = (__hip_bfloat16*)(ws + O_XCATL);
  float* regB = ws + O_REGB;
  u64*   kpart = (u64*)regB;                 // [M][8][20] u64 = 20.97MB
  float* tb    = regB;                       // [M, <=512] fp32 (after merge)
  __hip_bfloat16* XLH = (__hip_bfloat16*)regB;
  __hip_bfloat16* XLL = (__hip_bfloat16*)(regB + 4194304);
  float* logitsF = regB;
  __hip_bfloat16* H1H = (__hip_bfloat16*)(ws + O_H1H);
  __hip_bfloat16* H1L = (__hip_bfloat16*)(ws + O_H1L);
  __hip_bfloat16* H2H = (__hip_bfloat16*)(ws + O_H2H);
  __hip_bfloat16* H2L = (__hip_bfloat16*)(ws + O_H2L);

  // ---- detect + fused conversions ----
  detect_kernel<<<1, 256, 0, stream>>>(d_in[0], Mm*3, dflag);
  cvt_small_kernel<<<(49152+4096+5200+255)/256, 256, 0, stream>>>(ws, dflag,
      d_in[0], d_in[3], d_in[4], d_in[6], d_in[7], d_in[9], d_in[10], d_in[12], d_in[13],
      d_in[15], d_in[16], d_in[18], d_in[19], d_in[21], d_in[22], d_in[24], d_in[25], d_in[27]);
  cvt_w_kernel<<<(WTOT+255)/256, 256, 0, stream>>>(ws, dflag,
      d_in[14], d_in[17], d_in[20], d_in[23], d_in[26]);

  auto mgemm = [&](const __hip_bfloat16* Ah, const __hip_bfloat16* Al, int lda,
                   const __hip_bfloat16* Wh, const __hip_bfloat16* Wl, int ldw,
                   float* Cf, __hip_bfloat16* Ch, __hip_bfloat16* Cl, int ldc,
                   int K, int O, const float* sc, const float* bi, const float* av,
                   int lr, unsigned* pool){
    dim3 g((O+127)/128, Mm/128);
    mfma_gemm_kernel<<<g, 256, 0, stream>>>(Ah, Al, lda, Wh, Wl, ldw, Cf, Ch, Cl, ldc,
                                            K, O, sc, bi, av, lr, pool);
  };

  // ---- edgeconv layer 1 (C=3) ----
  norms_kernel<<<Mm/256, 256, 0, stream>>>(xyzf, 3, 3, nrm);
  knn3_kernel<<<dim3(Nn/256, Gg, Bb), 256, 0, stream>>>(xyzf, nrm, kpart);
  knn_final_merge_kernel<<<Mm/256, 256, 0, stream>>>(kpart, idx);
  prep_w1_kernel<<<1, 256, 0, stream>>>(ws, dflag, d_in[2]);
  gemm_kernel<<<dim3(2, Mm/64), 256, 0, stream>>>(xyzf, 3, ws + O_WCAT1, 3, tb, 128, 3, 128);
  gathermax_kernel<<<((size_t)Mm*64)/256, 256, 0, stream>>>(
      tb, idx, ws+O_S1, ws+O_B1, 64, XCH + 0, XCL + 0, 512);

  // ---- edgeconv layers 2-4 (MFMA path) ----
  struct LayerDef { int coff; int C; int O; size_t so, bo; int win; };
  LayerDef L[3] = {
    {0,   64, 64,  O_S2, O_B2, 5},
    {64,  64, 128, O_S3, O_B3, 8},
    {128, 128, 256, O_S4, O_B4, 11},
  };
  for (int li = 0; li < 3; ++li){
    int C = L[li].C, O = L[li].O, coff = L[li].coff;
    norms_hl_kernel<<<Mm/256, 256, 0, stream>>>(XCH + coff, XCL + coff, 512, C, nrm);
    if (C == 64)
      knn_mfma_kernel<64><<<dim3(Nn/64, Gg, Bb), 256, 0, stream>>>(XCH + coff, XCL + coff, 512, nrm, kpart);
    else
      knn_mfma_kernel<128><<<dim3(Nn/64, Gg, Bb), 256, 0, stream>>>(XCH + coff, XCL + coff, 512, nrm, kpart);
    knn_final_merge_kernel<<<Mm/256, 256, 0, stream>>>(kpart, idx);
    prep_w_hl_kernel<<<(O*C+255)/256, 256, 0, stream>>>(ws, dflag, d_in[L[li].win], C, O);
    mgemm(XCH + coff, XCL + coff, 512, WCH, WCL, C, tb, nullptr, nullptr, 2*O, C, 2*O,
          nullptr, nullptr, nullptr, 0, nullptr);
    gathermax_kernel<<<((size_t)Mm*O)/256, 256, 0, stream>>>(
        tb, idx, ws + L[li].so, ws + L[li].bo, O, XCH + coff + C, XCL + coff + C, 512);
  }

  // ---- chain ----
  mgemm(XCH, XCL, 512, WBH + WOF_WF, WBL + WOF_WF, 512, nullptr, XLH, XLL, 512,
        512, 512, ws+O_SF, ws+O_BF, nullptr, 1, nullptr);
  mgemm(XLH, XLL, 512, WBH + WOF_WE, WBL + WOF_WE, 512, nullptr, nullptr, nullptr, 0,
        512, 1024, ws+O_SE, ws+O_BE, nullptr, 1, glob);
  gvec_kernel<<<dim3(64, Bb), 256, 0, stream>>>(WBH + WOF_WH1, WBL + WOF_WH1, glob, gv);
  mgemm(XLH, XLL, 512, WBH + WOF_WH1, WBL + WOF_WH1, 1536, nullptr, H1H, H1L, 256,
        512, 256, ws+O_SH1, ws+O_BH1, gv, 1, nullptr);
  mgemm(H1H, H1L, 256, WBH + WOF_WH2, WBL + WOF_WH2, 256, nullptr, H2H, H2L, 256,
        256, 256, ws+O_SH2, ws+O_BH2, nullptr, 1, nullptr);
  mgemm(H2H, H2L, 256, WBH + WOF_WH3, WBL + WOF_WH3, 256, logitsF, nullptr, nullptr, 50,
        256, 50, nullptr, ws+O_BH3, nullptr, 0, nullptr);
  store_out_kernel<<<((size_t)Mm*50 + 255)/256, 256, 0, stream>>>(logitsF, dflag, d_out, Mm*50);
}

// Round 12
// 2373.999 us; speedup vs baseline: 1.3797x; 1.0022x over previous
//
#include <hip/hip_runtime.h>
#include <hip/hip_bf16.h>
#include <cstdint>

#define LEAKV 0.2f
static const int Bb = 4, Nn = 4096, Mm = 16384, Kk = 20;
static const int Gg = 8;

typedef __attribute__((ext_vector_type(8))) short bf16x8;
typedef __attribute__((ext_vector_type(4))) float f32x4;
typedef unsigned long long u64;

__device__ __forceinline__ float lrelu_f(float v){ return v > 0.f ? v : LEAKV*v; }

// ---------------- workspace layout (float offsets, compile-time) ----------------
constexpr size_t O_DFLAG = 0;
constexpr size_t O_XYZ   = 16;
constexpr size_t O_NRM   = 49168;
constexpr size_t O_IDX   = 65552;
constexpr size_t O_GLOB  = 393232;
constexpr size_t O_GV    = 397328;
constexpr size_t O_S1 = 398352, O_B1 = 398416, O_S2 = 398480, O_B2 = 398544;
constexpr size_t O_S3 = 398608, O_B3 = 398736, O_S4 = 398864, O_B4 = 399120;
constexpr size_t O_SF = 399376, O_BF = 399888, O_SE = 400400, O_BE = 401424;
constexpr size_t O_SH1 = 402448, O_BH1 = 402704, O_SH2 = 402960, O_BH2 = 403216;
constexpr size_t O_BH3 = 403472;
constexpr size_t O_WCAT1 = 403536;
constexpr size_t O_WBH  = 404992;
constexpr size_t O_WBL  = 1033984;
constexpr size_t O_WCATH = 1662976;
constexpr size_t O_WCATL = 1695744;
constexpr size_t O_XCATH = 1728512;
constexpr size_t O_XCATL = 5922816;
constexpr size_t O_REGB  = 10117120;
constexpr size_t O_H1H = O_XCATH;
constexpr size_t O_H1L = O_XCATH + 2097152;
constexpr size_t O_H2H = O_XCATH + 4194304;
constexpr size_t O_H2L = O_XCATH + 6291456;
constexpr size_t WOF_WF = 0, WOF_WE = 262144, WOF_WH1 = 786432, WOF_WH2 = 1179648, WOF_WH3 = 1245184;
constexpr int WTOT = 1257984;

// ---------- register-resident top-20 list (named scalars -> no scratch spill) ----------
#define REP20(X) X(0) X(1) X(2) X(3) X(4) X(5) X(6) X(7) X(8) X(9) X(10) X(11) X(12) X(13) X(14) X(15) X(16) X(17) X(18) X(19)
#define REP19(X) X(0,1) X(1,2) X(2,3) X(3,4) X(4,5) X(5,6) X(6,7) X(7,8) X(8,9) X(9,10) X(10,11) X(11,12) X(12,13) X(13,14) X(14,15) X(15,16) X(16,17) X(17,18) X(18,19)
struct KList {
#define KDECL(i) u64 k##i;
  REP20(KDECL)
#undef KDECL
  __device__ __forceinline__ void init(){
#define KINIT(i) k##i = ~0ULL;
    REP20(KINIT)
#undef KINIT
  }
  // maintains descending order (k0 = worst/largest, k19 = best/smallest)
  __device__ __forceinline__ void insert(u64 key){
    k0 = key;
#define KSWAP(a,b) { bool s_ = k##a < k##b; u64 mx_ = s_ ? k##b : k##a; u64 mn_ = s_ ? k##a : k##b; k##a = mx_; k##b = mn_; }
    REP19(KSWAP)
#undef KSWAP
  }
};

// ---------- dtype detector ----------
__global__ void detect_kernel(const void* __restrict__ xyz, int n, int* __restrict__ flag){
  __shared__ int cnt;
  if (threadIdx.x == 0) cnt = 0;
  __syncthreads();
  const __hip_bfloat16* p = (const __hip_bfloat16*)xyz;
  int local = 0;
  for (int i = threadIdx.x; i < n; i += 256){
    float v = __bfloat162float(p[i]);
    if (!(fabsf(v) < 1000.f)) local++;
  }
  atomicAdd(&cnt, local);
  __syncthreads();
  if (threadIdx.x == 0) *flag = (cnt < n/16) ? 1 : 0;   // 1 = bf16, 0 = fp32
}

__device__ __forceinline__ float rdval(const void* p, int i, int flag){
  return flag ? __bfloat162float(((const __hip_bfloat16*)p)[i]) : ((const float*)p)[i];
}

// ---------- fused small-input conversion + glob init ----------
__global__ void cvt_small_kernel(float* __restrict__ ws, const int* __restrict__ flag,
    const void* xyz, const void* s1, const void* b1, const void* s2, const void* b2,
    const void* s3, const void* b3, const void* s4, const void* b4,
    const void* sf, const void* bf, const void* se, const void* be,
    const void* sh1, const void* bh1, const void* sh2, const void* bh2, const void* bh3)
{
  int t = blockIdx.x*256 + threadIdx.x;
  int fl = *flag;
  if (t < 49152){ ws[O_XYZ + t] = rdval(xyz, t, fl); return; }
  t -= 49152;
  if (t < 4096){ ((unsigned*)(ws + O_GLOB))[t] = 0u; return; }
  t -= 4096;
  if (t < 64){ ws[O_S1+t] = rdval(s1,t,fl); return; }  t -= 64;
  if (t < 64){ ws[O_B1+t] = rdval(b1,t,fl); return; }  t -= 64;
  if (t < 64){ ws[O_S2+t] = rdval(s2,t,fl); return; }  t -= 64;
  if (t < 64){ ws[O_B2+t] = rdval(b2,t,fl); return; }  t -= 64;
  if (t < 128){ ws[O_S3+t] = rdval(s3,t,fl); return; } t -= 128;
  if (t < 128){ ws[O_B3+t] = rdval(b3,t,fl); return; } t -= 128;
  if (t < 256){ ws[O_S4+t] = rdval(s4,t,fl); return; } t -= 256;
  if (t < 256){ ws[O_B4+t] = rdval(b4,t,fl); return; } t -= 256;
  if (t < 512){ ws[O_SF+t] = rdval(sf,t,fl); return; } t -= 512;
  if (t < 512){ ws[O_BF+t] = rdval(bf,t,fl); return; } t -= 512;
  if (t < 1024){ ws[O_SE+t] = rdval(se,t,fl); return; } t -= 1024;
  if (t < 1024){ ws[O_BE+t] = rdval(be,t,fl); return; } t -= 1024;
  if (t < 256){ ws[O_SH1+t] = rdval(sh1,t,fl); return; } t -= 256;
  if (t < 256){ ws[O_BH1+t] = rdval(bh1,t,fl); return; } t -= 256;
  if (t < 256){ ws[O_SH2+t] = rdval(sh2,t,fl); return; } t -= 256;
  if (t < 256){ ws[O_BH2+t] = rdval(bh2,t,fl); return; } t -= 256;
  if (t < 50){ ws[O_BH3+t] = rdval(bh3,t,fl); return; }
}

// ---------- fused big-weight conversion -> bf16 hi/lo ----------
__global__ void cvt_w_kernel(float* __restrict__ ws, const int* __restrict__ flag,
    const void* wf, const void* we, const void* wh1, const void* wh2, const void* wh3)
{
  int t = blockIdx.x*256 + threadIdx.x;
  if (t >= WTOT) return;
  int fl = *flag;
  float v;
  if (t < (int)WOF_WE)        v = rdval(wf,  t, fl);
  else if (t < (int)WOF_WH1)  v = rdval(we,  t - WOF_WE, fl);
  else if (t < (int)WOF_WH2)  v = rdval(wh1, t - WOF_WH1, fl);
  else if (t < (int)WOF_WH3)  v = rdval(wh2, t - WOF_WH2, fl);
  else                        v = rdval(wh3, t - WOF_WH3, fl);
  __hip_bfloat16 h = __float2bfloat16(v);
  ((__hip_bfloat16*)(ws + O_WBH))[t] = h;
  ((__hip_bfloat16*)(ws + O_WBL))[t] = __float2bfloat16(v - __bfloat162float(h));
}

// ---------- edgeconv weight prep: wcat = [w_d ; w_x - w_d] -> bf16 h/l ----------
__global__ void prep_w_hl_kernel(float* __restrict__ ws, const int* __restrict__ flag,
                                 const void* __restrict__ w, int C, int O){
  int t = blockIdx.x*256 + threadIdx.x;
  if (t >= O*C) return;
  int fl = *flag;
  int o = t / C, c = t - o*C;
  float wd = rdval(w, o*2*C + c, fl);
  float wx = rdval(w, o*2*C + C + c, fl);
  float dx = wx - wd;
  __hip_bfloat16* Wh = (__hip_bfloat16*)(ws + O_WCATH);
  __hip_bfloat16* Wl = (__hip_bfloat16*)(ws + O_WCATL);
  __hip_bfloat16 h1 = __float2bfloat16(wd);
  Wh[o*C + c] = h1; Wl[o*C + c] = __float2bfloat16(wd - __bfloat162float(h1));
  __hip_bfloat16 h2 = __float2bfloat16(dx);
  Wh[(O+o)*C + c] = h2; Wl[(O+o)*C + c] = __float2bfloat16(dx - __bfloat162float(h2));
}

// layer-1 fp32 wcat [128][3]
__global__ void prep_w1_kernel(float* __restrict__ ws, const int* __restrict__ flag,
                               const void* __restrict__ w){
  int t = blockIdx.x*256 + threadIdx.x;
  if (t >= 64*3) return;
  int fl = *flag;
  int o = t / 3, c = t - o*3;
  float wd = rdval(w, o*6 + c, fl);
  float wx = rdval(w, o*6 + 3 + c, fl);
  ws[O_WCAT1 + o*3 + c] = wd;
  ws[O_WCAT1 + (64+o)*3 + c] = wx - wd;
}

// ---------- norms ----------
__global__ void norms_kernel(const float* __restrict__ x, int ld, int C, float* __restrict__ out){
  int t = blockIdx.x*256 + threadIdx.x;
  if (t >= Mm) return;
  const float* r = x + (size_t)t*ld;
  float s = 0.f;
  for (int c = 0; c < C; ++c){ float v = r[c]; s += v*v; }
  out[t] = s;
}
__global__ void norms_hl_kernel(const __hip_bfloat16* __restrict__ Xh, const __hip_bfloat16* __restrict__ Xl,
                                int ld, int C, float* __restrict__ out){
  int t = blockIdx.x*256 + threadIdx.x;
  if (t >= Mm) return;
  size_t base = (size_t)t*ld;
  float s = 0.f;
  for (int c = 0; c < C; ++c){
    float v = __bfloat162float(Xh[base+c]) + __bfloat162float(Xl[base+c]);
    s += v*v;
  }
  out[t] = s;
}

__device__ __forceinline__ unsigned fkey(float f){
  unsigned u = __float_as_uint(f);
  return (u & 0x80000000u) ? ~u : (u | 0x80000000u);
}
__device__ __forceinline__ float funkey(unsigned k){
  if (k == 0u) return -1e30f;
  unsigned u = (k & 0x80000000u) ? (k ^ 0x80000000u) : ~k;
  return __uint_as_float(u);
}

// ---------- MFMA KNN: wave owns 16 queries; packed-u64 register-resident selection ----------
template<int C>
__global__ __launch_bounds__(256, 4) void knn_mfma_kernel(
    const __hip_bfloat16* __restrict__ Xh, const __hip_bfloat16* __restrict__ Xl, int lda,
    const float* __restrict__ n2,
    u64* __restrict__ kpart)
{
  constexpr int KS = C/32;
  __shared__ __align__(16) char smem[40960];
  const int tid = threadIdx.x;
  const int lane = tid & 63;
  const int w = tid >> 6;
  const int b = blockIdx.z, bN = b*Nn;
  const int q0 = blockIdx.x*64 + w*16;
  const int g = blockIdx.y;
  const int kq = (lane >> 4) * 8;
  float* dtw = (float*)(smem + w*10240);
  u64* sm64 = (u64*)(smem + w*10240);

  bf16x8 Ah[KS], Al[KS];
  {
    const size_t qrow = (size_t)(bN + q0 + (lane & 15))*lda;
    #pragma unroll
    for (int s = 0; s < KS; ++s){
      Ah[s] = *reinterpret_cast<const bf16x8*>(Xh + qrow + s*32 + kq);
      Al[s] = *reinterpret_cast<const bf16x8*>(Xl + qrow + s*32 + kq);
    }
  }

  KList kl; kl.init();

  const int NT = (Nn/Gg)/16;
  for (int jt = 0; jt < NT; ++jt){
    const int j0 = g*(Nn/Gg) + jt*16;
    const size_t crow = (size_t)(bN + j0 + (lane & 15))*lda;
    f32x4 acc = {0.f, 0.f, 0.f, 0.f};
    #pragma unroll
    for (int s = 0; s < KS; ++s){
      bf16x8 Bh = *reinterpret_cast<const bf16x8*>(Xh + crow + s*32 + kq);
      bf16x8 Bl = *reinterpret_cast<const bf16x8*>(Xl + crow + s*32 + kq);
      acc = __builtin_amdgcn_mfma_f32_16x16x32_bf16(Ah[s], Bh, acc, 0, 0, 0);
      acc = __builtin_amdgcn_mfma_f32_16x16x32_bf16(Ah[s], Bl, acc, 0, 0, 0);
      acc = __builtin_amdgcn_mfma_f32_16x16x32_bf16(Al[s], Bh, acc, 0, 0, 0);
    }
    float nj = n2[bN + j0 + (lane & 15)];
    const int rbase = (lane >> 4)*4;
    #pragma unroll
    for (int r = 0; r < 4; ++r)
      dtw[(rbase + r)*17 + (lane & 15)] = nj - 2.f*acc[r];
    const float* rowp = dtw + (lane >> 2)*17 + (lane & 3)*4;
    #pragma unroll
    for (int t = 0; t < 4; ++t){
      float d = rowp[t];
      u64 key = ((u64)fkey(d) << 32) | (unsigned)(j0 + (lane & 3)*4 + t);
      if (key < kl.k0) kl.insert(key);
    }
  }

  // dump sorted (descending) list to the wave's LDS slab
#define KDUMP(i) sm64[lane*20 + (i)] = kl.k##i;
  REP20(KDUMP)
#undef KDUMP
  // quad leader: 4-way merge of ascending streams (pop from tail)
  if ((lane & 3) == 0){
    unsigned hpack = 0x13131313u;   // four 8-bit heads = 19
    u64 v0 = sm64[(lane+0)*20 + 19];
    u64 v1 = sm64[(lane+1)*20 + 19];
    u64 v2 = sm64[(lane+2)*20 + 19];
    u64 v3 = sm64[(lane+3)*20 + 19];
    const int q = q0 + (lane >> 2);
    u64* outp = kpart + ((size_t)(bN + q)*Gg + g)*20;
    #pragma unroll
    for (int r = 0; r < 20; ++r){
      u64 m01 = v0 < v1 ? v0 : v1; int p01 = v0 < v1 ? 0 : 1;
      u64 m23 = v2 < v3 ? v2 : v3; int p23 = v2 < v3 ? 2 : 3;
      bool f01 = m01 < m23;
      u64 mv = f01 ? m01 : m23;
      int mp = f01 ? p01 : p23;
      outp[r] = mv;
      int sh = mp*8;
      int h = (int)((hpack >> sh) & 0xffu) - 1;
      hpack -= (1u << sh);
      int hc = h < 0 ? 0 : h;
      u64 rv = sm64[(lane + mp)*20 + hc];
      u64 nv = (h >= 0) ? rv : ~0ULL;
      v0 = (mp == 0) ? nv : v0;
      v1 = (mp == 1) ? nv : v1;
      v2 = (mp == 2) ? nv : v2;
      v3 = (mp == 3) ? nv : v3;
    }
  }
}

// ---------- KNN for C=3: packed-u64 register-resident selection ----------
__global__ __launch_bounds__(256, 4) void knn3_kernel(
    const float* __restrict__ x, const float* __restrict__ n2,
    u64* __restrict__ kpart)
{
  __shared__ __align__(16) float cs[512*4];
  const int tid = threadIdx.x;
  const int b = blockIdx.z, bN = b*Nn;
  const int g = blockIdx.y;                 // 0..7
  const int q = blockIdx.x*256 + tid;
  float qx = x[(size_t)(bN+q)*3 + 0];
  float qy = x[(size_t)(bN+q)*3 + 1];
  float qz = x[(size_t)(bN+q)*3 + 2];
  for (int e = tid; e < 512; e += 256){
    int j = g*512 + e;
    cs[e*4+0] = x[(size_t)(bN+j)*3 + 0];
    cs[e*4+1] = x[(size_t)(bN+j)*3 + 1];
    cs[e*4+2] = x[(size_t)(bN+j)*3 + 2];
    cs[e*4+3] = n2[bN+j];
  }
  __syncthreads();
  KList kl; kl.init();
  for (int t = 0; t < 512; ++t){
    float4 c = *reinterpret_cast<const float4*>(&cs[t*4]);
    float d = c.w - 2.f*(qx*c.x + qy*c.y + qz*c.z);
    u64 key = ((u64)fkey(d) << 32) | (unsigned)(g*512 + t);
    if (key < kl.k0) kl.insert(key);
  }
  u64* outp = kpart + ((size_t)(bN + q)*Gg + g)*20;
#define KOUT3(i) outp[19-(i)] = kl.k##i;
  REP20(KOUT3)
#undef KOUT3
}

// ---------- final merge: Gg sorted ascending 20-lists -> top-20 ----------
__global__ __launch_bounds__(256, 4) void knn_final_merge_kernel(
    const u64* __restrict__ kpart, int* __restrict__ idx)
{
  int t = blockIdx.x*256 + threadIdx.x;
  if (t >= Mm) return;
  const u64* base = kpart + (size_t)t*Gg*20;
  KList kl; kl.init();
  for (int g = 0; g < Gg; ++g){
    const u64* lp = base + g*20;
    #pragma unroll 1
    for (int l = 0; l < 20; ++l){
      u64 key = lp[l];
      if (key >= kl.k0) break;     // sorted -> rest are larger
      kl.insert(key);
    }
  }
#define KOUTI(i) idx[(size_t)t*Kk + (19-(i))] = (int)(kl.k##i & 0xffffffffu);
  REP20(KOUTI)
#undef KOUTI
}

// ---------- gather-max epilogue: fp32 tb -> bf16 h/l activations ----------
__global__ void gathermax_kernel(const float* __restrict__ tb, const int* __restrict__ idx,
                                 const float* __restrict__ sv, const float* __restrict__ bv,
                                 int O, __hip_bfloat16* __restrict__ outh,
                                 __hip_bfloat16* __restrict__ outl, int ldo)
{
  int t = blockIdx.x*256 + threadIdx.x;
  int o = t % O;
  int m = t / O;           // b*N + i
  int b = m / Nn;
  const int twoO = 2*O;
  const int* ip = idx + (size_t)m*Kk;
  float mx = -1e30f;
  for (int j = 0; j < Kk; ++j){
    int jj = ip[j] & (Nn-1);
    mx = fmaxf(mx, tb[(size_t)(b*Nn + jj)*twoO + o]);
  }
  float basev = tb[(size_t)m*twoO + O + o];
  float y = lrelu_f((mx + basev) * sv[o] + bv[o]);
  __hip_bfloat16 h = __float2bfloat16(y);
  outh[(size_t)m*ldo + o] = h;
  outl[(size_t)m*ldo + o] = __float2bfloat16(y - __bfloat162float(h));
}

// ---------- MFMA GEMM (LDS-staged): C[M,O] = (Ah+Al)[M,K] @ (Wh+Wl)[O,K]^T ----------
__global__ __launch_bounds__(256) void mfma_gemm_kernel(
    const __hip_bfloat16* __restrict__ Ah, const __hip_bfloat16* __restrict__ Al, int lda,
    const __hip_bfloat16* __restrict__ Wh, const __hip_bfloat16* __restrict__ Wl, int ldw,
    float* __restrict__ Cf, __hip_bfloat16* __restrict__ Ch, __hip_bfloat16* __restrict__ Cl, int ldc,
    int K, int O,
    const float* __restrict__ scale, const float* __restrict__ bias,
    const float* __restrict__ addvec, int lrelu_flag,
    unsigned* __restrict__ pool)
{
  constexpr int LDK = 40;
  __shared__ __align__(16) __hip_bfloat16 AsH[128*LDK];
  __shared__ __align__(16) __hip_bfloat16 AsL[128*LDK];
  __shared__ __align__(16) __hip_bfloat16 BsH[128*LDK];
  __shared__ __align__(16) __hip_bfloat16 BsL[128*LDK];
  __shared__ float redp[2][128];
  const int tid = threadIdx.x;
  const int lane = tid & 63, w = tid >> 6;
  const int o0 = blockIdx.x*128, m0 = blockIdx.y*128;
  const int wr = (w >> 1)*64, wc = (w & 1)*64;
  const int kq = (lane >> 4)*8;
  const int fr = lane & 15;
  f32x4 acc[4][4] = {};

  for (int k0 = 0; k0 < K; k0 += 32){
    __syncthreads();
    #pragma unroll
    for (int j = 0; j < 2; ++j){
      int chunk = tid + j*256;
      int r = chunk >> 2, k8 = (chunk & 3)*8;
      size_t ga = (size_t)(m0 + r)*lda + k0 + k8;
      int oo = o0 + r; if (oo >= O) oo = O - 1;
      size_t gb = (size_t)oo*ldw + k0 + k8;
      int ls = r*LDK + k8;
      *reinterpret_cast<bf16x8*>(&AsH[ls]) = *reinterpret_cast<const bf16x8*>(Ah + ga);
      *reinterpret_cast<bf16x8*>(&AsL[ls]) = *reinterpret_cast<const bf16x8*>(Al + ga);
      *reinterpret_cast<bf16x8*>(&BsH[ls]) = *reinterpret_cast<const bf16x8*>(Wh + gb);
      *reinterpret_cast<bf16x8*>(&BsL[ls]) = *reinterpret_cast<const bf16x8*>(Wl + gb);
    }
    __syncthreads();
    bf16x8 ah[4], al[4];
    #pragma unroll
    for (int mi = 0; mi < 4; ++mi){
      int ls = (wr + mi*16 + fr)*LDK + kq;
      ah[mi] = *reinterpret_cast<const bf16x8*>(&AsH[ls]);
      al[mi] = *reinterpret_cast<const bf16x8*>(&AsL[ls]);
    }
    #pragma unroll
    for (int ni = 0; ni < 4; ++ni){
      int ls = (wc + ni*16 + fr)*LDK + kq;
      bf16x8 bh = *reinterpret_cast<const bf16x8*>(&BsH[ls]);
      bf16x8 bl = *reinterpret_cast<const bf16x8*>(&BsL[ls]);
      #pragma unroll
      for (int mi = 0; mi < 4; ++mi){
        acc[mi][ni] = __builtin_amdgcn_mfma_f32_16x16x32_bf16(ah[mi], bh, acc[mi][ni], 0, 0, 0);
        acc[mi][ni] = __builtin_amdgcn_mfma_f32_16x16x32_bf16(ah[mi], bl, acc[mi][ni], 0, 0, 0);
        acc[mi][ni] = __builtin_amdgcn_mfma_f32_16x16x32_bf16(al[mi], bh, acc[mi][ni], 0, 0, 0);
      }
    }
  }
  const int b = m0 / Nn;
  if (pool){
    #pragma unroll
    for (int ni = 0; ni < 4; ++ni){
      int o = o0 + wc + ni*16 + fr;
      float sc_ = scale[o], bi_ = bias[o];
      float m = -1e30f;
      #pragma unroll
      for (int mi = 0; mi < 4; ++mi)
        #pragma unroll
        for (int r = 0; r < 4; ++r)
          m = fmaxf(m, lrelu_f(acc[mi][ni][r]*sc_ + bi_));
      m = fmaxf(m, __shfl_xor(m, 16, 64));
      m = fmaxf(m, __shfl_xor(m, 32, 64));
      if ((lane >> 4) == 0) redp[w >> 1][wc + ni*16 + fr] = m;
    }
    __syncthreads();
    if (tid < 128){
      float m = fmaxf(redp[0][tid], redp[1][tid]);
      atomicMax(&pool[b*O + o0 + tid], fkey(m));
    }
    return;
  }
  #pragma unroll
  for (int ni = 0; ni < 4; ++ni){
    int o = o0 + wc + ni*16 + fr;
    if (o >= O) continue;
    float sc_ = scale ? scale[o] : 1.f;
    float bi_ = bias ? bias[o] : 0.f;
    float av  = addvec ? addvec[b*O + o] : 0.f;
    #pragma unroll
    for (int mi = 0; mi < 4; ++mi){
      #pragma unroll
      for (int r = 0; r < 4; ++r){
        int m = m0 + wr + mi*16 + (lane >> 4)*4 + r;
        float y = acc[mi][ni][r] + av;
        if (scale) y = y*sc_ + bi_;
        else       y = y + bi_;
        if (lrelu_flag) y = lrelu_f(y);
        if (Ch){
          __hip_bfloat16 h = __float2bfloat16(y);
          Ch[(size_t)m*ldc + o] = h;
          Cl[(size_t)m*ldc + o] = __float2bfloat16(y - __bfloat162float(h));
        } else {
          Cf[(size_t)m*ldc + o] = y;
        }
      }
    }
  }
}

// ---------- fp32 GEMM (layer-1 tb only, K=3) ----------
__global__ __launch_bounds__(256) void gemm_kernel(
    const float* __restrict__ A, int lda,
    const float* __restrict__ W, int ldw,
    float* __restrict__ Cf, int ldc, int K, int O)
{
  const int tid = threadIdx.x;
  const int tx = tid & 15, ty = tid >> 4;
  const int m0 = blockIdx.y * 64;
  const int o0 = blockIdx.x * 64;
  __shared__ __align__(16) float As[16*68];
  __shared__ __align__(16) float Ws[16*68];
  float acc[4][4] = {};
  for (int k0 = 0; k0 < K; k0 += 16){
    __syncthreads();
    #pragma unroll
    for (int r = 0; r < 4; ++r){
      int e = tid + r*256;
      int k = e & 15, mi = e >> 4;
      int kk = k0 + k;
      float v = 0.f, wv = 0.f;
      if (kk < K) v = A[(size_t)(m0+mi)*lda + kk];
      int oo = o0 + mi;
      if (kk < K && oo < O) wv = W[(size_t)oo*ldw + kk];
      As[k*68 + mi] = v;
      Ws[k*68 + mi] = wv;
    }
    __syncthreads();
    #pragma unroll
    for (int kk = 0; kk < 16; ++kk){
      float4 av = *reinterpret_cast<const float4*>(&As[kk*68 + ty*4]);
      float4 wv = *reinterpret_cast<const float4*>(&Ws[kk*68 + tx*4]);
      float a4[4] = {av.x, av.y, av.z, av.w};
      float w4[4] = {wv.x, wv.y, wv.z, wv.w};
      #pragma unroll
      for (int i = 0; i < 4; ++i)
        #pragma unroll
        for (int j = 0; j < 4; ++j)
          acc[i][j] += a4[i]*w4[j];
    }
  }
  #pragma unroll
  for (int i = 0; i < 4; ++i){
    int m = m0 + ty*4 + i;
    #pragma unroll
    for (int j = 0; j < 4; ++j){
      int o = o0 + tx*4 + j;
      if (o >= O) continue;
      Cf[(size_t)m*ldc + o] = acc[i][j];
    }
  }
}

// gvec[b,o2] = sum_c wh1[o2, 512+c] * glob[b,c]
__global__ void gvec_kernel(const __hip_bfloat16* __restrict__ Wh, const __hip_bfloat16* __restrict__ Wl,
                            const unsigned* __restrict__ glob, float* __restrict__ gv){
  int lane = threadIdx.x & 63, w = threadIdx.x >> 6;
  int o2 = blockIdx.x*4 + w;
  int b = blockIdx.y;
  size_t base = (size_t)o2*1536 + 512;
  float s = 0.f;
  for (int c = lane; c < 1024; c += 64){
    float wv = __bfloat162float(Wh[base+c]) + __bfloat162float(Wl[base+c]);
    s += wv * funkey(glob[b*1024 + c]);
  }
  #pragma unroll
  for (int off = 32; off >= 1; off >>= 1) s += __shfl_xor(s, off, 64);
  if (lane == 0) gv[b*256 + o2] = s;
}

// ---------- flag-gated output store ----------
__global__ void store_out_kernel(const float* __restrict__ src, const int* __restrict__ flag,
                                 void* __restrict__ dst, int n){
  int t = blockIdx.x*256 + threadIdx.x;
  if (t >= n) return;
  float v = src[t];
  if (*flag) ((__hip_bfloat16*)dst)[t] = __float2bfloat16(v);
  else       ((float*)dst)[t] = v;
}

extern "C" void kernel_launch(void* const* d_in, const int* in_sizes, int n_in,
                              void* d_out, int out_size, void* d_ws, size_t ws_size,
                              hipStream_t stream) {
  (void)in_sizes; (void)n_in; (void)out_size; (void)ws_size;
  float* ws = (float*)d_ws;
  int* dflag = (int*)(ws + O_DFLAG);
  float* xyzf = ws + O_XYZ;
  float* nrm  = ws + O_NRM;
  int*   idx  = (int*)(ws + O_IDX);
  unsigned* glob = (unsigned*)(ws + O_GLOB);
  float* gv = ws + O_GV;
  __hip_bfloat16* WBH = (__hip_bfloat16*)(ws + O_WBH);
  __hip_bfloat16* WBL = (__hip_bfloat16*)(ws + O_WBL);
  __hip_bfloat16* WCH = (__hip_bfloat16*)(ws + O_WCATH);
  __hip_bfloat16* WCL = (__hip_bfloat16*)(ws + O_WCATL);
  __hip_bfloat16* XCH = (__hip_bfloat16*)(ws + O_XCATH);
  __hip_bfloat16* XCL = (__hip_bfloat16*)(ws + O_XCATL);
  float* regB = ws + O_REGB;
  u64*   kpart = (u64*)regB;
  float* tb    = regB;
  __hip_bfloat16* XLH = (__hip_bfloat16*)regB;
  __hip_bfloat16* XLL = (__hip_bfloat16*)(regB + 4194304);
  float* logitsF = regB;
  __hip_bfloat16* H1H = (__hip_bfloat16*)(ws + O_H1H);
  __hip_bfloat16* H1L = (__hip_bfloat16*)(ws + O_H1L);
  __hip_bfloat16* H2H = (__hip_bfloat16*)(ws + O_H2H);
  __hip_bfloat16* H2L = (__hip_bfloat16*)(ws + O_H2L);

  // ---- detect + fused conversions ----
  detect_kernel<<<1, 256, 0, stream>>>(d_in[0], Mm*3, dflag);
  cvt_small_kernel<<<(49152+4096+5200+255)/256, 256, 0, stream>>>(ws, dflag,
      d_in[0], d_in[3], d_in[4], d_in[6], d_in[7], d_in[9], d_in[10], d_in[12], d_in[13],
      d_in[15], d_in[16], d_in[18], d_in[19], d_in[21], d_in[22], d_in[24], d_in[25], d_in[27]);
  cvt_w_kernel<<<(WTOT+255)/256, 256, 0, stream>>>(ws, dflag,
      d_in[14], d_in[17], d_in[20], d_in[23], d_in[26]);

  auto mgemm = [&](const __hip_bfloat16* Ah, const __hip_bfloat16* Al, int lda,
                   const __hip_bfloat16* Wh, const __hip_bfloat16* Wl, int ldw,
                   float* Cf, __hip_bfloat16* Ch, __hip_bfloat16* Cl, int ldc,
                   int K, int O, const float* sc, const float* bi, const float* av,
                   int lr, unsigned* pool){
    dim3 g((O+127)/128, Mm/128);
    mfma_gemm_kernel<<<g, 256, 0, stream>>>(Ah, Al, lda, Wh, Wl, ldw, Cf, Ch, Cl, ldc,
                                            K, O, sc, bi, av, lr, pool);
  };

  // ---- edgeconv layer 1 (C=3) ----
  norms_kernel<<<Mm/256, 256, 0, stream>>>(xyzf, 3, 3, nrm);
  knn3_kernel<<<dim3(Nn/256, Gg, Bb), 256, 0, stream>>>(xyzf, nrm, kpart);
  knn_final_merge_kernel<<<Mm/256, 256, 0, stream>>>(kpart, idx);
  prep_w1_kernel<<<1, 256, 0, stream>>>(ws, dflag, d_in[2]);
  gemm_kernel<<<dim3(2, Mm/64), 256, 0, stream>>>(xyzf, 3, ws + O_WCAT1, 3, tb, 128, 3, 128);
  gathermax_kernel<<<((size_t)Mm*64)/256, 256, 0, stream>>>(
      tb, idx, ws+O_S1, ws+O_B1, 64, XCH + 0, XCL + 0, 512);

  // ---- edgeconv layers 2-4 (MFMA path) ----
  struct LayerDef { int coff; int C; int O; size_t so, bo; int win; };
  LayerDef L[3] = {
    {0,   64, 64,  O_S2, O_B2, 5},
    {64,  64, 128, O_S3, O_B3, 8},
    {128, 128, 256, O_S4, O_B4, 11},
  };
  for (int li = 0; li < 3; ++li){
    int C = L[li].C, O = L[li].O, coff = L[li].coff;
    norms_hl_kernel<<<Mm/256, 256, 0, stream>>>(XCH + coff, XCL + coff, 512, C, nrm);
    if (C == 64)
      knn_mfma_kernel<64><<<dim3(Nn/64, Gg, Bb), 256, 0, stream>>>(XCH + coff, XCL + coff, 512, nrm, kpart);
    else
      knn_mfma_kernel<128><<<dim3(Nn/64, Gg, Bb), 256, 0, stream>>>(XCH + coff, XCL + coff, 512, nrm, kpart);
    knn_final_merge_kernel<<<Mm/256, 256, 0, stream>>>(kpart, idx);
    prep_w_hl_kernel<<<(O*C+255)/256, 256, 0, stream>>>(ws, dflag, d_in[L[li].win], C, O);
    mgemm(XCH + coff, XCL + coff, 512, WCH, WCL, C, tb, nullptr, nullptr, 2*O, C, 2*O,
          nullptr, nullptr, nullptr, 0, nullptr);
    gathermax_kernel<<<((size_t)Mm*O)/256, 256, 0, stream>>>(
        tb, idx, ws + L[li].so, ws + L[li].bo, O, XCH + coff + C, XCL + coff + C, 512);
  }

  // ---- chain ----
  mgemm(XCH, XCL, 512, WBH + WOF_WF, WBL + WOF_WF, 512, nullptr, XLH, XLL, 512,
        512, 512, ws+O_SF, ws+O_BF, nullptr, 1, nullptr);
  mgemm(XLH, XLL, 512, WBH + WOF_WE, WBL + WOF_WE, 512, nullptr, nullptr, nullptr, 0,
        512, 1024, ws+O_SE, ws+O_BE, nullptr, 1, glob);
  gvec_kernel<<<dim3(64, Bb), 256, 0, stream>>>(WBH + WOF_WH1, WBL + WOF_WH1, glob, gv);
  mgemm(XLH, XLL, 512, WBH + WOF_WH1, WBL + WOF_WH1, 1536, nullptr, H1H, H1L, 256,
        512, 256, ws+O_SH1, ws+O_BH1, gv, 1, nullptr);
  mgemm(H1H, H1L, 256, WBH + WOF_WH2, WBL + WOF_WH2, 256, nullptr, H2H, H2L, 256,
        256, 256, ws+O_SH2, ws+O_BH2, nullptr, 1, nullptr);
  mgemm(H2H, H2L, 256, WBH + WOF_WH3, WBL + WOF_WH3, 256, logitsF, nullptr, nullptr, 50,
        256, 50, nullptr, ws+O_BH3, nullptr, 0, nullptr);
  store_out_kernel<<<((size_t)Mm*50 + 255)/256, 256, 0, stream>>>(logitsF, dflag, d_out, Mm*50);
}